// Round 6
// baseline (342.525 us; speedup 1.0000x reference)
//
#include <hip/hip_runtime.h>
#include <math.h>

#define NN 50000
#define EE 800000
#define IN_C 128
#define HID 64
#define HEADS 4
#define SCAN_BLOCKS ((NN + 255) / 256)   // 196
#define EBLOCKS ((EE + 255) / 256)       // 3125
#define GEMM1B ((NN + 31) / 32)          // 1563

typedef __attribute__((ext_vector_type(8))) short bf16x8;
typedef __attribute__((ext_vector_type(4))) float f32x4;

#if defined(__has_builtin)
#if __has_builtin(__builtin_amdgcn_fdot2_f32_bf16)
#define HAVE_FDOT2_BF16 1
#endif
#endif

// ---------------- helpers ----------------

__device__ inline unsigned short f2bf(float f) {       // fp32 -> bf16 RNE
    unsigned u = __float_as_uint(f);
    return (unsigned short)((u + 0x7fff + ((u >> 16) & 1)) >> 16);
}
__device__ inline float bf2f(unsigned short s) {
    return __uint_as_float(((unsigned)s) << 16);
}
__device__ inline unsigned prm(unsigned a, unsigned b, unsigned sel) {
    return __builtin_amdgcn_perm(a, b, sel);
}
// (lo16(pairA), lo16(pairB)) dot (w pair) + acc ; a-edge in low half, b-edge in high half
#ifdef HAVE_FDOT2_BF16
typedef __attribute__((ext_vector_type(2))) __bf16 bf2v;
__device__ inline float fdot2bf(unsigned h, unsigned w, float acc) {
    return __builtin_amdgcn_fdot2_f32_bf16(__builtin_bit_cast(bf2v, h),
                                           __builtin_bit_cast(bf2v, w), acc, false);
}
#else
__device__ inline float fdot2bf(unsigned h, unsigned w, float acc) {
    return acc + bf2f((unsigned short)(h & 0xffff)) * bf2f((unsigned short)(w & 0xffff))
               + bf2f((unsigned short)(h >> 16)) * bf2f((unsigned short)(w >> 16));
}
#endif

__device__ inline int wave_incl_scan(int v, int lane) {
    #pragma unroll
    for (int off = 1; off < 64; off <<= 1) {
        int t = __shfl_up(v, off);
        if (lane >= off) v += t;
    }
    return v;
}

__device__ inline int block256_excl_scan(int v, int tid, int* ws4) {
    int lane = tid & 63, wv = tid >> 6;
    int incl = wave_incl_scan(v, lane);
    if (lane == 63) ws4[wv] = incl;
    __syncthreads();
    if (tid == 0) {
        int run = 0;
        #pragma unroll
        for (int i = 0; i < 4; i++) { int t = ws4[i]; ws4[i] = run; run += t; }
    }
    __syncthreads();
    return incl + ws4[wv] - v;
}

// ---------------- front: degree histogram + weight transpose/splits ----------------

__global__ void front_kernel(const int* __restrict__ ei, int* __restrict__ deg,
                             const float* __restrict__ W1, unsigned short* __restrict__ W1Thi,
                             unsigned short* __restrict__ W1Tlo,
                             const float* __restrict__ W2, unsigned short* __restrict__ W2Thi,
                             unsigned short* __restrict__ W2Tlo) {
    int b = blockIdx.x;
    int tid = threadIdx.x;
    if (b < EBLOCKS) {
        int i = b * 256 + tid;
        if (i < EE) atomicAdd(&deg[ei[EE + i]], 1);
    } else if (b < EBLOCKS + 128) {
        int idx = (b - EBLOCKS) * 256 + tid;         // W1 [128][256]
        int r = idx >> 8, c = idx & 255;
        float v = W1[idx];
        unsigned short h = f2bf(v);
        W1Thi[c * 128 + r] = h;
        W1Tlo[c * 128 + r] = f2bf(v - bf2f(h));
    } else {
        int idx = (b - EBLOCKS - 128) * 256 + tid;   // W2 [256][64]
        int r = idx >> 6, c = idx & 63;
        float v = W2[idx];
        unsigned short h = f2bf(v);
        W2Thi[c * 256 + r] = h;
        W2Tlo[c * 256 + r] = f2bf(v - bf2f(h));
    }
}

// ---------------- CSR scan chain ----------------

__global__ void deg_partial_kernel(const int* __restrict__ deg, int* __restrict__ bsum) {
    __shared__ int ws4[4];
    int tid = threadIdx.x;
    int idx = blockIdx.x * 256 + tid;
    int d = (idx < NN) ? deg[idx] : 0;
    int lane = tid & 63, wv = tid >> 6;
    int s = d;
    #pragma unroll
    for (int off = 32; off; off >>= 1) s += __shfl_down(s, off);
    if (lane == 0) ws4[wv] = s;
    __syncthreads();
    if (tid == 0) bsum[blockIdx.x] = ws4[0] + ws4[1] + ws4[2] + ws4[3];
}

__global__ void scanb_kernel(const int* __restrict__ bsum, int* __restrict__ boff,
                             int* __restrict__ row_ptr) {
    __shared__ int ws4[4];
    int tid = threadIdx.x;
    int v = (tid < SCAN_BLOCKS) ? bsum[tid] : 0;
    int excl = block256_excl_scan(v, tid, ws4);
    if (tid < SCAN_BLOCKS) boff[tid] = excl;
    if (tid == 255) row_ptr[NN] = excl + v;   // == EE
}

__global__ void fill_kernel(const int* __restrict__ deg, const int* __restrict__ boff,
                            int* __restrict__ row_ptr, int* __restrict__ cursor) {
    __shared__ int ws4[4];
    int tid = threadIdx.x;
    int idx = blockIdx.x * 256 + tid;
    int d = (idx < NN) ? deg[idx] : 0;
    int excl = block256_excl_scan(d, tid, ws4) + boff[blockIdx.x];
    if (idx < NN) { row_ptr[idx] = excl; cursor[idx] = excl; }
}

// ---------------- fat kernel: edge scatter (CSR fill) + layer-1 MFMA GEMM ----------------
// blocks [0,EBLOCKS) scatter; blocks [EBLOCKS, EBLOCKS+GEMM1B) do gemm1 (indep. work overlaps)
__global__ __launch_bounds__(256) void scatter_gemm1_kernel(
        const int* __restrict__ ei, int* __restrict__ cursor, int* __restrict__ csr_src,
        const float* __restrict__ x,
        const unsigned short* __restrict__ Bhi, const unsigned short* __restrict__ Blo,
        const float* __restrict__ a_src, const float* __restrict__ a_dst,
        unsigned short* __restrict__ h1b, float* __restrict__ as1, float* __restrict__ ad1) {
    __shared__ unsigned short Ahi[32][136];   // +8 pad
    __shared__ unsigned short Alo[32][136];
    int tid = threadIdx.x;
    if (blockIdx.x < EBLOCKS) {
        int i = blockIdx.x * 256 + tid;
        if (i < EE) {
            int d = ei[EE + i];
            int pos = atomicAdd(&cursor[d], 1);
            csr_src[pos] = ei[i];
        }
        return;
    }
    int w = tid >> 6, lane = tid & 63;
    int lq = lane >> 4, lr = lane & 15;
    int brow = (blockIdx.x - EBLOCKS) * 32;
    // stage 32x128 of x -> bf16 hi/lo in LDS
    {
        int row = tid >> 3;
        int col0 = (tid & 7) * 16;
        int gr = min(brow + row, NN - 1);
        #pragma unroll
        for (int i = 0; i < 16; i += 4) {
            float4 v = *(const float4*)(x + (size_t)gr * 128 + col0 + i);
            unsigned short h0 = f2bf(v.x), h1 = f2bf(v.y), h2 = f2bf(v.z), h3 = f2bf(v.w);
            Ahi[row][col0 + i + 0] = h0; Alo[row][col0 + i + 0] = f2bf(v.x - bf2f(h0));
            Ahi[row][col0 + i + 1] = h1; Alo[row][col0 + i + 1] = f2bf(v.y - bf2f(h1));
            Ahi[row][col0 + i + 2] = h2; Alo[row][col0 + i + 2] = f2bf(v.z - bf2f(h2));
            Ahi[row][col0 + i + 3] = h3; Alo[row][col0 + i + 3] = f2bf(v.w - bf2f(h3));
        }
    }
    __syncthreads();
    f32x4 acc[2][4];
    f32x4 zf = {0.f, 0.f, 0.f, 0.f};
    #pragma unroll
    for (int mi = 0; mi < 2; mi++)
        #pragma unroll
        for (int ni = 0; ni < 4; ni++) acc[mi][ni] = zf;
    #pragma unroll
    for (int q = 0; q < 4; q++) {
        int ko = q * 32 + lq * 8;
        bf16x8 ah0 = *(const bf16x8*)(const void*)&Ahi[lr][ko];
        bf16x8 al0 = *(const bf16x8*)(const void*)&Alo[lr][ko];
        bf16x8 ah1 = *(const bf16x8*)(const void*)&Ahi[16 + lr][ko];
        bf16x8 al1 = *(const bf16x8*)(const void*)&Alo[16 + lr][ko];
        #pragma unroll
        for (int ni = 0; ni < 4; ni++) {
            size_t bo = (size_t)(w * 64 + ni * 16 + lr) * 128 + ko;
            bf16x8 bh = *(const bf16x8*)(const void*)(Bhi + bo);
            bf16x8 bl = *(const bf16x8*)(const void*)(Blo + bo);
            acc[0][ni] = __builtin_amdgcn_mfma_f32_16x16x32_bf16(al0, bh, acc[0][ni], 0, 0, 0);
            acc[0][ni] = __builtin_amdgcn_mfma_f32_16x16x32_bf16(ah0, bl, acc[0][ni], 0, 0, 0);
            acc[0][ni] = __builtin_amdgcn_mfma_f32_16x16x32_bf16(ah0, bh, acc[0][ni], 0, 0, 0);
            acc[1][ni] = __builtin_amdgcn_mfma_f32_16x16x32_bf16(al1, bh, acc[1][ni], 0, 0, 0);
            acc[1][ni] = __builtin_amdgcn_mfma_f32_16x16x32_bf16(ah1, bl, acc[1][ni], 0, 0, 0);
            acc[1][ni] = __builtin_amdgcn_mfma_f32_16x16x32_bf16(ah1, bh, acc[1][ni], 0, 0, 0);
        }
    }
    float asv[4], adv[4];
    #pragma unroll
    for (int ni = 0; ni < 4; ni++) {
        asv[ni] = a_src[w * 64 + ni * 16 + lr];
        adv[ni] = a_dst[w * 64 + ni * 16 + lr];
    }
    #pragma unroll
    for (int mi = 0; mi < 2; mi++) {
        f32x4 ps = zf, pd = zf;
        #pragma unroll
        for (int ni = 0; ni < 4; ni++)
            #pragma unroll
            for (int r = 0; r < 4; r++) {
                ps[r] += acc[mi][ni][r] * asv[ni];
                pd[r] += acc[mi][ni][r] * adv[ni];
            }
        #pragma unroll
        for (int m = 1; m < 16; m <<= 1)
            #pragma unroll
            for (int r = 0; r < 4; r++) {
                ps[r] += __shfl_xor(ps[r], m);
                pd[r] += __shfl_xor(pd[r], m);
            }
        #pragma unroll
        for (int r = 0; r < 4; r++) {
            int n = brow + mi * 16 + lq * 4 + r;
            if (lr == 0 && n < NN) { as1[n * 4 + w] = ps[r]; ad1[n * 4 + w] = pd[r]; }
        }
        #pragma unroll
        for (int ni = 0; ni < 4; ni++)
            #pragma unroll
            for (int r = 0; r < 4; r++) {
                int n = brow + mi * 16 + lq * 4 + r;
                if (n < NN)
                    h1b[(size_t)n * 256 + w * 64 + ni * 16 + lr] = f2bf(acc[mi][ni][r]);
            }
    }
}

// ---------------- layer-2 MFMA GEMM + fused alpha ----------------
__global__ __launch_bounds__(256) void gemm2_mfma(
        const unsigned short* __restrict__ Ahi, const unsigned short* __restrict__ Alo,
        const unsigned short* __restrict__ Bhi, const unsigned short* __restrict__ Blo,
        const float* __restrict__ a_src, const float* __restrict__ a_dst,
        unsigned short* __restrict__ g2b, float* __restrict__ as2, float* __restrict__ ad2) {
    int tid = threadIdx.x;
    int w = tid >> 6, lane = tid & 63;
    int lq = lane >> 4, lr = lane & 15;
    int wrow = blockIdx.x * 128 + w * 32;
    f32x4 acc[2][4];
    f32x4 zf = {0.f, 0.f, 0.f, 0.f};
    #pragma unroll
    for (int mi = 0; mi < 2; mi++)
        #pragma unroll
        for (int ni = 0; ni < 4; ni++) acc[mi][ni] = zf;
    int ra = min(wrow + lr, NN - 1);
    int rb = min(wrow + 16 + lr, NN - 1);
    #pragma unroll
    for (int q = 0; q < 8; q++) {
        int ko = q * 32 + lq * 8;
        bf16x8 ah0 = *(const bf16x8*)(const void*)(Ahi + (size_t)ra * 256 + ko);
        bf16x8 al0 = *(const bf16x8*)(const void*)(Alo + (size_t)ra * 256 + ko);
        bf16x8 ah1 = *(const bf16x8*)(const void*)(Ahi + (size_t)rb * 256 + ko);
        bf16x8 al1 = *(const bf16x8*)(const void*)(Alo + (size_t)rb * 256 + ko);
        #pragma unroll
        for (int ni = 0; ni < 4; ni++) {
            size_t bo = (size_t)(ni * 16 + lr) * 256 + ko;
            bf16x8 bh = *(const bf16x8*)(const void*)(Bhi + bo);
            bf16x8 bl = *(const bf16x8*)(const void*)(Blo + bo);
            acc[0][ni] = __builtin_amdgcn_mfma_f32_16x16x32_bf16(al0, bh, acc[0][ni], 0, 0, 0);
            acc[0][ni] = __builtin_amdgcn_mfma_f32_16x16x32_bf16(ah0, bl, acc[0][ni], 0, 0, 0);
            acc[0][ni] = __builtin_amdgcn_mfma_f32_16x16x32_bf16(ah0, bh, acc[0][ni], 0, 0, 0);
            acc[1][ni] = __builtin_amdgcn_mfma_f32_16x16x32_bf16(al1, bh, acc[1][ni], 0, 0, 0);
            acc[1][ni] = __builtin_amdgcn_mfma_f32_16x16x32_bf16(ah1, bl, acc[1][ni], 0, 0, 0);
            acc[1][ni] = __builtin_amdgcn_mfma_f32_16x16x32_bf16(ah1, bh, acc[1][ni], 0, 0, 0);
        }
    }
    float asv[4], adv[4];
    #pragma unroll
    for (int ni = 0; ni < 4; ni++) {
        asv[ni] = a_src[ni * 16 + lr];
        adv[ni] = a_dst[ni * 16 + lr];
    }
    #pragma unroll
    for (int mi = 0; mi < 2; mi++) {
        f32x4 ps = zf, pd = zf;
        #pragma unroll
        for (int ni = 0; ni < 4; ni++)
            #pragma unroll
            for (int r = 0; r < 4; r++) {
                ps[r] += acc[mi][ni][r] * asv[ni];
                pd[r] += acc[mi][ni][r] * adv[ni];
            }
        #pragma unroll
        for (int m = 1; m < 16; m <<= 1)
            #pragma unroll
            for (int r = 0; r < 4; r++) {
                ps[r] += __shfl_xor(ps[r], m);
                pd[r] += __shfl_xor(pd[r], m);
            }
        #pragma unroll
        for (int r = 0; r < 4; r++) {
            int n = wrow + mi * 16 + lq * 4 + r;
            if (lr == 0 && n < NN) { as2[n] = ps[r]; ad2[n] = pd[r]; }
        }
        #pragma unroll
        for (int ni = 0; ni < 4; ni++)
            #pragma unroll
            for (int r = 0; r < 4; r++) {
                int n = wrow + mi * 16 + lq * 4 + r;
                if (n < NN)
                    g2b[(size_t)n * 64 + ni * 16 + lr] = f2bf(acc[mi][ni][r]);
            }
    }
}

// ---------------- layer-1 aggregation: edge-paired dot2 gather ----------------
__global__ __launch_bounds__(256) void agg1_kernel(
        const unsigned short* __restrict__ h1b, const int* __restrict__ row_ptr,
        const int* __restrict__ csr_src, const float* __restrict__ as,
        const float* __restrict__ ad, const float* __restrict__ b1,
        unsigned short* __restrict__ h2hi, unsigned short* __restrict__ h2lo) {
    __shared__ int            ssrc[4][64];
    __shared__ unsigned short wbf[4][4][64];   // [wave][head][edge] bf16 weights
    int tid = threadIdx.x;
    int wv = tid >> 6, lane = tid & 63;
    int n = blockIdx.x * 4 + wv;
    if (n >= NN) return;
    int start = row_ptr[n], end = row_ptr[n + 1];
    float4 adv = ((const float4*)ad)[n];
    int whead = lane >> 4;
    float4 acc = make_float4(0.f, 0.f, 0.f, 0.f);
    float d0 = 0.f, d1 = 0.f, d2 = 0.f, d3 = 0.f;
    for (int c0 = start; c0 < end; c0 += 64) {
        int m = min(64, end - c0);
        if (lane < m) {
            int s = csr_src[c0 + lane];
            ssrc[wv][lane] = s;
            float4 asv = ((const float4*)as)[s];
            float e0 = asv.x + adv.x; e0 = e0 > 0.f ? e0 : 0.2f * e0; float x0 = __expf(e0);
            float e1 = asv.y + adv.y; e1 = e1 > 0.f ? e1 : 0.2f * e1; float x1 = __expf(e1);
            float e2 = asv.z + adv.z; e2 = e2 > 0.f ? e2 : 0.2f * e2; float x2 = __expf(e2);
            float e3 = asv.w + adv.w; e3 = e3 > 0.f ? e3 : 0.2f * e3; float x3 = __expf(e3);
            wbf[wv][0][lane] = f2bf(x0);
            wbf[wv][1][lane] = f2bf(x1);
            wbf[wv][2][lane] = f2bf(x2);
            wbf[wv][3][lane] = f2bf(x3);
            d0 += x0; d1 += x1; d2 += x2; d3 += x3;
        }
        int j = 0;
        for (; j + 4 <= m; j += 4) {
            int s0 = ssrc[wv][j], s1 = ssrc[wv][j + 1];
            int s2 = ssrc[wv][j + 2], s3 = ssrc[wv][j + 3];
            uint2 ha = ((const uint2*)h1b)[(size_t)s0 * 64 + lane];
            uint2 hb = ((const uint2*)h1b)[(size_t)s1 * 64 + lane];
            uint2 hc = ((const uint2*)h1b)[(size_t)s2 * 64 + lane];
            uint2 hd = ((const uint2*)h1b)[(size_t)s3 * 64 + lane];
            unsigned wp01 = *(const unsigned*)&wbf[wv][whead][j];
            unsigned wp23 = *(const unsigned*)&wbf[wv][whead][j + 2];
            acc.x = fdot2bf(prm(hb.x, ha.x, 0x05040100), wp01, acc.x);
            acc.y = fdot2bf(prm(hb.x, ha.x, 0x07060302), wp01, acc.y);
            acc.z = fdot2bf(prm(hb.y, ha.y, 0x05040100), wp01, acc.z);
            acc.w = fdot2bf(prm(hb.y, ha.y, 0x07060302), wp01, acc.w);
            acc.x = fdot2bf(prm(hd.x, hc.x, 0x05040100), wp23, acc.x);
            acc.y = fdot2bf(prm(hd.x, hc.x, 0x07060302), wp23, acc.y);
            acc.z = fdot2bf(prm(hd.y, hc.y, 0x05040100), wp23, acc.z);
            acc.w = fdot2bf(prm(hd.y, hc.y, 0x07060302), wp23, acc.w);
        }
        for (; j + 2 <= m; j += 2) {
            int s0 = ssrc[wv][j], s1 = ssrc[wv][j + 1];
            uint2 ha = ((const uint2*)h1b)[(size_t)s0 * 64 + lane];
            uint2 hb = ((const uint2*)h1b)[(size_t)s1 * 64 + lane];
            unsigned wp = *(const unsigned*)&wbf[wv][whead][j];
            acc.x = fdot2bf(prm(hb.x, ha.x, 0x05040100), wp, acc.x);
            acc.y = fdot2bf(prm(hb.x, ha.x, 0x07060302), wp, acc.y);
            acc.z = fdot2bf(prm(hb.y, ha.y, 0x05040100), wp, acc.z);
            acc.w = fdot2bf(prm(hb.y, ha.y, 0x07060302), wp, acc.w);
        }
        if (j < m) {
            int s = ssrc[wv][j];
            float w = bf2f(wbf[wv][whead][j]);
            ushort4 hv = ((const ushort4*)h1b)[(size_t)s * 64 + lane];
            acc.x += bf2f(hv.x) * w; acc.y += bf2f(hv.y) * w;
            acc.z += bf2f(hv.z) * w; acc.w += bf2f(hv.w) * w;
        }
    }
    #pragma unroll
    for (int off = 32; off; off >>= 1) {
        d0 += __shfl_down(d0, off); d1 += __shfl_down(d1, off);
        d2 += __shfl_down(d2, off); d3 += __shfl_down(d3, off);
    }
    d0 = __shfl(d0, 0); d1 = __shfl(d1, 0);
    d2 = __shfl(d2, 0); d3 = __shfl(d3, 0);
    float den = whead == 0 ? d0 : whead == 1 ? d1 : whead == 2 ? d2 : d3;
    float inv = 1.f / (den + 1e-16f);
    float4 bv = ((const float4*)b1)[lane];
    float4 r;
    r.x = acc.x * inv + bv.x; r.y = acc.y * inv + bv.y;
    r.z = acc.z * inv + bv.z; r.w = acc.w * inv + bv.w;
    r.x = r.x > 0.f ? r.x : expm1f(r.x);
    r.y = r.y > 0.f ? r.y : expm1f(r.y);
    r.z = r.z > 0.f ? r.z : expm1f(r.z);
    r.w = r.w > 0.f ? r.w : expm1f(r.w);
    ushort4 hi4, lo4;
    hi4.x = f2bf(r.x); lo4.x = f2bf(r.x - bf2f(hi4.x));
    hi4.y = f2bf(r.y); lo4.y = f2bf(r.y - bf2f(hi4.y));
    hi4.z = f2bf(r.z); lo4.z = f2bf(r.z - bf2f(hi4.z));
    hi4.w = f2bf(r.w); lo4.w = f2bf(r.w - bf2f(hi4.w));
    ((ushort4*)h2hi)[(size_t)n * 64 + lane] = hi4;
    ((ushort4*)h2lo)[(size_t)n * 64 + lane] = lo4;
}

// ---------------- layer-2 aggregation: edge-paired dot2 gather ----------------
__global__ __launch_bounds__(256) void agg2_kernel(
        const unsigned short* __restrict__ g2b, const int* __restrict__ row_ptr,
        const int* __restrict__ csr_src, const float* __restrict__ as,
        const float* __restrict__ ad, const float* __restrict__ b2,
        float* __restrict__ out) {
    __shared__ int            ssrc[4][64];
    __shared__ unsigned short wbf[4][64];
    int tid = threadIdx.x;
    int wv = tid >> 6, lane = tid & 63;
    int n = blockIdx.x * 4 + wv;
    if (n >= NN) return;
    int start = row_ptr[n], end = row_ptr[n + 1];
    float adv = ad[n];
    float acc = 0.f;
    float den = 0.f;
    for (int c0 = start; c0 < end; c0 += 64) {
        int m = min(64, end - c0);
        if (lane < m) {
            int s = csr_src[c0 + lane];
            ssrc[wv][lane] = s;
            float e = as[s] + adv;
            e = e > 0.f ? e : 0.2f * e;
            float x = __expf(e);
            wbf[wv][lane] = f2bf(x);
            den += x;
        }
        int j = 0;
        for (; j + 4 <= m; j += 4) {
            int s0 = ssrc[wv][j], s1 = ssrc[wv][j + 1];
            int s2 = ssrc[wv][j + 2], s3 = ssrc[wv][j + 3];
            unsigned g0 = g2b[(size_t)s0 * 64 + lane];
            unsigned g1 = g2b[(size_t)s1 * 64 + lane];
            unsigned g2 = g2b[(size_t)s2 * 64 + lane];
            unsigned g3 = g2b[(size_t)s3 * 64 + lane];
            unsigned wp01 = *(const unsigned*)&wbf[wv][j];
            unsigned wp23 = *(const unsigned*)&wbf[wv][j + 2];
            acc = fdot2bf(prm(g1, g0, 0x05040100), wp01, acc);
            acc = fdot2bf(prm(g3, g2, 0x05040100), wp23, acc);
        }
        for (; j + 2 <= m; j += 2) {
            int s0 = ssrc[wv][j], s1 = ssrc[wv][j + 1];
            unsigned g0 = g2b[(size_t)s0 * 64 + lane];
            unsigned g1 = g2b[(size_t)s1 * 64 + lane];
            unsigned wp = *(const unsigned*)&wbf[wv][j];
            acc = fdot2bf(prm(g1, g0, 0x05040100), wp, acc);
        }
        if (j < m) {
            int s = ssrc[wv][j];
            acc += bf2f(g2b[(size_t)s * 64 + lane]) * bf2f(wbf[wv][j]);
        }
    }
    #pragma unroll
    for (int off = 32; off; off >>= 1) den += __shfl_down(den, off);
    den = __shfl(den, 0);
    float inv = 1.f / (den + 1e-16f);
    float r = acc * inv + b2[lane];
    out[(size_t)n * 64 + lane] = r > 0.f ? r : expm1f(r);
}

// ---------------- launch ----------------

extern "C" void kernel_launch(void* const* d_in, const int* in_sizes, int n_in,
                              void* d_out, int out_size, void* d_ws, size_t ws_size,
                              hipStream_t stream) {
    const float* x      = (const float*)d_in[0];
    const int*   ei     = (const int*)d_in[1];
    const float* W1     = (const float*)d_in[2];
    const float* a_src1 = (const float*)d_in[3];
    const float* a_dst1 = (const float*)d_in[4];
    const float* b1     = (const float*)d_in[5];
    const float* W2     = (const float*)d_in[6];
    const float* a_src2 = (const float*)d_in[7];
    const float* a_dst2 = (const float*)d_in[8];
    const float* b2     = (const float*)d_in[9];
    float* out = (float*)d_out;

    char* base = (char*)d_ws;
    size_t off = 0;
    auto alloc = [&](size_t bytes) -> void* {
        void* p = base + off;
        off = (off + bytes + 255) & ~(size_t)255;
        return p;
    };
    int*   deg     = (int*)alloc(NN * sizeof(int));
    int*   bsum    = (int*)alloc(SCAN_BLOCKS * sizeof(int));
    int*   boff    = (int*)alloc(SCAN_BLOCKS * sizeof(int));
    int*   row_ptr = (int*)alloc((NN + 1) * sizeof(int));
    int*   cursor  = (int*)alloc(NN * sizeof(int));
    int*   csr_src = (int*)alloc(EE * sizeof(int));
    unsigned short* W1Thi = (unsigned short*)alloc(256 * 128 * 2);
    unsigned short* W1Tlo = (unsigned short*)alloc(256 * 128 * 2);
    unsigned short* W2Thi = (unsigned short*)alloc(64 * 256 * 2);
    unsigned short* W2Tlo = (unsigned short*)alloc(64 * 256 * 2);
    unsigned short* h1b   = (unsigned short*)alloc((size_t)NN * 256 * 2);
    float* as1     = (float*)alloc((size_t)NN * 4 * sizeof(float));
    float* ad1     = (float*)alloc((size_t)NN * 4 * sizeof(float));
    unsigned short* h2hi  = (unsigned short*)alloc((size_t)NN * 256 * 2);
    unsigned short* h2lo  = (unsigned short*)alloc((size_t)NN * 256 * 2);
    unsigned short* g2b   = (unsigned short*)alloc((size_t)NN * 64 * 2);
    float* as2     = (float*)alloc((size_t)NN * sizeof(float));
    float* ad2     = (float*)alloc((size_t)NN * sizeof(float));

    hipMemsetAsync(deg, 0, NN * sizeof(int), stream);

    front_kernel<<<EBLOCKS + 128 + 64, 256, 0, stream>>>(ei, deg, W1, W1Thi, W1Tlo,
                                                         W2, W2Thi, W2Tlo);
    deg_partial_kernel<<<SCAN_BLOCKS, 256, 0, stream>>>(deg, bsum);
    scanb_kernel<<<1, 256, 0, stream>>>(bsum, boff, row_ptr);
    fill_kernel<<<SCAN_BLOCKS, 256, 0, stream>>>(deg, boff, row_ptr, cursor);

    // scatter (CSR fill) overlapped with layer-1 GEMM (independent work)
    scatter_gemm1_kernel<<<EBLOCKS + GEMM1B, 256, 0, stream>>>(
        ei, cursor, csr_src, x, W1Thi, W1Tlo, a_src1, a_dst1, h1b, as1, ad1);

    agg1_kernel<<<(NN + 3) / 4, 256, 0, stream>>>(h1b, row_ptr, csr_src, as1, ad1, b1,
                                                  h2hi, h2lo);
    gemm2_mfma<<<(NN + 127) / 128, 256, 0, stream>>>(h2hi, h2lo, W2Thi, W2Tlo,
                                                     a_src2, a_dst2, g2b, as2, ad2);
    agg2_kernel<<<(NN + 3) / 4, 256, 0, stream>>>(g2b, row_ptr, csr_src, as2, ad2, b2, out);
}

// Round 7
// 291.900 us; speedup vs baseline: 1.1734x; 1.1734x over previous
//
#include <hip/hip_runtime.h>
#include <math.h>

#define NN 50000
#define EE 800000
#define IN_C 128
#define HID 64
#define HEADS 4
#define SCAN_BLOCKS ((NN + 255) / 256)   // 196
#define EBLOCKS ((EE + 255) / 256)       // 3125

typedef __attribute__((ext_vector_type(8))) short bf16x8;
typedef __attribute__((ext_vector_type(4))) float f32x4;

#if defined(__has_builtin)
#if __has_builtin(__builtin_amdgcn_fdot2_f32_bf16)
#define HAVE_FDOT2_BF16 1
#endif
#endif

// ---------------- helpers ----------------

__device__ inline unsigned short f2bf(float f) {       // fp32 -> bf16 RNE
    unsigned u = __float_as_uint(f);
    return (unsigned short)((u + 0x7fff + ((u >> 16) & 1)) >> 16);
}
__device__ inline float bf2f(unsigned short s) {
    return __uint_as_float(((unsigned)s) << 16);
}
__device__ inline unsigned prm(unsigned a, unsigned b, unsigned sel) {
    return __builtin_amdgcn_perm(a, b, sel);
}
#ifdef HAVE_FDOT2_BF16
typedef __attribute__((ext_vector_type(2))) __bf16 bf2v;
__device__ inline float fdot2bf(unsigned h, unsigned w, float acc) {
    return __builtin_amdgcn_fdot2_f32_bf16(__builtin_bit_cast(bf2v, h),
                                           __builtin_bit_cast(bf2v, w), acc, false);
}
#else
__device__ inline float fdot2bf(unsigned h, unsigned w, float acc) {
    return acc + bf2f((unsigned short)(h & 0xffff)) * bf2f((unsigned short)(w & 0xffff))
               + bf2f((unsigned short)(h >> 16)) * bf2f((unsigned short)(w >> 16));
}
#endif

__device__ inline int wave_incl_scan(int v, int lane) {
    #pragma unroll
    for (int off = 1; off < 64; off <<= 1) {
        int t = __shfl_up(v, off);
        if (lane >= off) v += t;
    }
    return v;
}

__device__ inline int block256_excl_scan(int v, int tid, int* ws4) {
    int lane = tid & 63, wv = tid >> 6;
    int incl = wave_incl_scan(v, lane);
    if (lane == 63) ws4[wv] = incl;
    __syncthreads();
    if (tid == 0) {
        int run = 0;
        #pragma unroll
        for (int i = 0; i < 4; i++) { int t = ws4[i]; ws4[i] = run; run += t; }
    }
    __syncthreads();
    return incl + ws4[wv] - v;
}

// ---------------- front: degree histogram (+edge ranks) + weight splits ----------------

__global__ void front_kernel(const int* __restrict__ ei, int* __restrict__ deg,
                             int* __restrict__ rank,
                             const float* __restrict__ W1, unsigned short* __restrict__ W1Thi,
                             unsigned short* __restrict__ W1Tlo,
                             const float* __restrict__ W2, unsigned short* __restrict__ W2Thi,
                             unsigned short* __restrict__ W2Tlo) {
    int b = blockIdx.x;
    int tid = threadIdx.x;
    if (b < EBLOCKS) {
        int i = b * 256 + tid;
        if (i < EE) rank[i] = atomicAdd(&deg[ei[EE + i]], 1);
    } else if (b < EBLOCKS + 128) {
        int idx = (b - EBLOCKS) * 256 + tid;         // W1 [128][256]
        int r = idx >> 8, c = idx & 255;
        float v = W1[idx];
        unsigned short h = f2bf(v);
        W1Thi[c * 128 + r] = h;
        W1Tlo[c * 128 + r] = f2bf(v - bf2f(h));
    } else {
        int idx = (b - EBLOCKS - 128) * 256 + tid;   // W2 [256][64]
        int r = idx >> 6, c = idx & 63;
        float v = W2[idx];
        unsigned short h = f2bf(v);
        W2Thi[c * 256 + r] = h;
        W2Tlo[c * 256 + r] = f2bf(v - bf2f(h));
    }
}

// ---------------- CSR scan chain ----------------

__global__ void deg_partial_kernel(const int* __restrict__ deg, int* __restrict__ bsum) {
    __shared__ int ws4[4];
    int tid = threadIdx.x;
    int idx = blockIdx.x * 256 + tid;
    int d = (idx < NN) ? deg[idx] : 0;
    int lane = tid & 63, wv = tid >> 6;
    int s = d;
    #pragma unroll
    for (int off = 32; off; off >>= 1) s += __shfl_down(s, off);
    if (lane == 0) ws4[wv] = s;
    __syncthreads();
    if (tid == 0) bsum[blockIdx.x] = ws4[0] + ws4[1] + ws4[2] + ws4[3];
}

__global__ void scanb_kernel(const int* __restrict__ bsum, int* __restrict__ boff,
                             int* __restrict__ row_ptr) {
    __shared__ int ws4[4];
    int tid = threadIdx.x;
    int v = (tid < SCAN_BLOCKS) ? bsum[tid] : 0;
    int excl = block256_excl_scan(v, tid, ws4);
    if (tid < SCAN_BLOCKS) boff[tid] = excl;
    if (tid == 255) row_ptr[NN] = excl + v;   // == EE
}

__global__ void fill_kernel(const int* __restrict__ deg, const int* __restrict__ boff,
                            int* __restrict__ row_ptr) {
    __shared__ int ws4[4];
    int tid = threadIdx.x;
    int idx = blockIdx.x * 256 + tid;
    int d = (idx < NN) ? deg[idx] : 0;
    int excl = block256_excl_scan(d, tid, ws4) + boff[blockIdx.x];
    if (idx < NN) row_ptr[idx] = excl;
}

// atomic-free scatter: position = row_ptr[dst] + precomputed rank
__global__ void scatter_kernel(const int* __restrict__ ei, const int* __restrict__ rank,
                               const int* __restrict__ row_ptr, int* __restrict__ csr_src) {
    int i = blockIdx.x * blockDim.x + threadIdx.x;
    if (i < EE) {
        int d = ei[EE + i];
        csr_src[row_ptr[d] + rank[i]] = ei[i];
    }
}

// ---------------- layer-1 MFMA GEMM + fused alpha ----------------
// h1 = x @ W1 (50000x128 @ 128x256). A staged+split in LDS once per block.
__global__ __launch_bounds__(256) void gemm1_mfma(
        const float* __restrict__ x,
        const unsigned short* __restrict__ Bhi, const unsigned short* __restrict__ Blo,
        const float* __restrict__ a_src, const float* __restrict__ a_dst,
        unsigned short* __restrict__ h1b, float* __restrict__ as1, float* __restrict__ ad1) {
    __shared__ unsigned short Ahi[32][136];   // +8 pad
    __shared__ unsigned short Alo[32][136];
    int tid = threadIdx.x;
    int w = tid >> 6, lane = tid & 63;
    int lq = lane >> 4, lr = lane & 15;
    int brow = blockIdx.x * 32;
    {
        int row = tid >> 3;
        int col0 = (tid & 7) * 16;
        int gr = min(brow + row, NN - 1);
        #pragma unroll
        for (int i = 0; i < 16; i += 4) {
            float4 v = *(const float4*)(x + (size_t)gr * 128 + col0 + i);
            unsigned short h0 = f2bf(v.x), h1 = f2bf(v.y), h2 = f2bf(v.z), h3 = f2bf(v.w);
            Ahi[row][col0 + i + 0] = h0; Alo[row][col0 + i + 0] = f2bf(v.x - bf2f(h0));
            Ahi[row][col0 + i + 1] = h1; Alo[row][col0 + i + 1] = f2bf(v.y - bf2f(h1));
            Ahi[row][col0 + i + 2] = h2; Alo[row][col0 + i + 2] = f2bf(v.z - bf2f(h2));
            Ahi[row][col0 + i + 3] = h3; Alo[row][col0 + i + 3] = f2bf(v.w - bf2f(h3));
        }
    }
    __syncthreads();
    f32x4 acc[2][4];
    f32x4 zf = {0.f, 0.f, 0.f, 0.f};
    #pragma unroll
    for (int mi = 0; mi < 2; mi++)
        #pragma unroll
        for (int ni = 0; ni < 4; ni++) acc[mi][ni] = zf;
    #pragma unroll
    for (int q = 0; q < 4; q++) {
        int ko = q * 32 + lq * 8;
        bf16x8 ah0 = *(const bf16x8*)(const void*)&Ahi[lr][ko];
        bf16x8 al0 = *(const bf16x8*)(const void*)&Alo[lr][ko];
        bf16x8 ah1 = *(const bf16x8*)(const void*)&Ahi[16 + lr][ko];
        bf16x8 al1 = *(const bf16x8*)(const void*)&Alo[16 + lr][ko];
        #pragma unroll
        for (int ni = 0; ni < 4; ni++) {
            size_t bo = (size_t)(w * 64 + ni * 16 + lr) * 128 + ko;
            bf16x8 bh = *(const bf16x8*)(const void*)(Bhi + bo);
            bf16x8 bl = *(const bf16x8*)(const void*)(Blo + bo);
            acc[0][ni] = __builtin_amdgcn_mfma_f32_16x16x32_bf16(al0, bh, acc[0][ni], 0, 0, 0);
            acc[0][ni] = __builtin_amdgcn_mfma_f32_16x16x32_bf16(ah0, bl, acc[0][ni], 0, 0, 0);
            acc[0][ni] = __builtin_amdgcn_mfma_f32_16x16x32_bf16(ah0, bh, acc[0][ni], 0, 0, 0);
            acc[1][ni] = __builtin_amdgcn_mfma_f32_16x16x32_bf16(al1, bh, acc[1][ni], 0, 0, 0);
            acc[1][ni] = __builtin_amdgcn_mfma_f32_16x16x32_bf16(ah1, bl, acc[1][ni], 0, 0, 0);
            acc[1][ni] = __builtin_amdgcn_mfma_f32_16x16x32_bf16(ah1, bh, acc[1][ni], 0, 0, 0);
        }
    }
    float asv[4], adv[4];
    #pragma unroll
    for (int ni = 0; ni < 4; ni++) {
        asv[ni] = a_src[w * 64 + ni * 16 + lr];
        adv[ni] = a_dst[w * 64 + ni * 16 + lr];
    }
    #pragma unroll
    for (int mi = 0; mi < 2; mi++) {
        f32x4 ps = zf, pd = zf;
        #pragma unroll
        for (int ni = 0; ni < 4; ni++)
            #pragma unroll
            for (int r = 0; r < 4; r++) {
                ps[r] += acc[mi][ni][r] * asv[ni];
                pd[r] += acc[mi][ni][r] * adv[ni];
            }
        #pragma unroll
        for (int m = 1; m < 16; m <<= 1)
            #pragma unroll
            for (int r = 0; r < 4; r++) {
                ps[r] += __shfl_xor(ps[r], m);
                pd[r] += __shfl_xor(pd[r], m);
            }
        #pragma unroll
        for (int r = 0; r < 4; r++) {
            int n = brow + mi * 16 + lq * 4 + r;
            if (lr == 0 && n < NN) { as1[n * 4 + w] = ps[r]; ad1[n * 4 + w] = pd[r]; }
        }
        #pragma unroll
        for (int ni = 0; ni < 4; ni++)
            #pragma unroll
            for (int r = 0; r < 4; r++) {
                int n = brow + mi * 16 + lq * 4 + r;
                if (n < NN)
                    h1b[(size_t)n * 256 + w * 64 + ni * 16 + lr] = f2bf(acc[mi][ni][r]);
            }
    }
}

// ---------------- layer-2 MFMA GEMM + fused alpha ----------------
__global__ __launch_bounds__(256) void gemm2_mfma(
        const unsigned short* __restrict__ Ahi, const unsigned short* __restrict__ Alo,
        const unsigned short* __restrict__ Bhi, const unsigned short* __restrict__ Blo,
        const float* __restrict__ a_src, const float* __restrict__ a_dst,
        unsigned short* __restrict__ g2b, float* __restrict__ as2, float* __restrict__ ad2) {
    int tid = threadIdx.x;
    int w = tid >> 6, lane = tid & 63;
    int lq = lane >> 4, lr = lane & 15;
    int wrow = blockIdx.x * 128 + w * 32;
    f32x4 acc[2][4];
    f32x4 zf = {0.f, 0.f, 0.f, 0.f};
    #pragma unroll
    for (int mi = 0; mi < 2; mi++)
        #pragma unroll
        for (int ni = 0; ni < 4; ni++) acc[mi][ni] = zf;
    int ra = min(wrow + lr, NN - 1);
    int rb = min(wrow + 16 + lr, NN - 1);
    #pragma unroll
    for (int q = 0; q < 8; q++) {
        int ko = q * 32 + lq * 8;
        bf16x8 ah0 = *(const bf16x8*)(const void*)(Ahi + (size_t)ra * 256 + ko);
        bf16x8 al0 = *(const bf16x8*)(const void*)(Alo + (size_t)ra * 256 + ko);
        bf16x8 ah1 = *(const bf16x8*)(const void*)(Ahi + (size_t)rb * 256 + ko);
        bf16x8 al1 = *(const bf16x8*)(const void*)(Alo + (size_t)rb * 256 + ko);
        #pragma unroll
        for (int ni = 0; ni < 4; ni++) {
            size_t bo = (size_t)(ni * 16 + lr) * 256 + ko;
            bf16x8 bh = *(const bf16x8*)(const void*)(Bhi + bo);
            bf16x8 bl = *(const bf16x8*)(const void*)(Blo + bo);
            acc[0][ni] = __builtin_amdgcn_mfma_f32_16x16x32_bf16(al0, bh, acc[0][ni], 0, 0, 0);
            acc[0][ni] = __builtin_amdgcn_mfma_f32_16x16x32_bf16(ah0, bl, acc[0][ni], 0, 0, 0);
            acc[0][ni] = __builtin_amdgcn_mfma_f32_16x16x32_bf16(ah0, bh, acc[0][ni], 0, 0, 0);
            acc[1][ni] = __builtin_amdgcn_mfma_f32_16x16x32_bf16(al1, bh, acc[1][ni], 0, 0, 0);
            acc[1][ni] = __builtin_amdgcn_mfma_f32_16x16x32_bf16(ah1, bl, acc[1][ni], 0, 0, 0);
            acc[1][ni] = __builtin_amdgcn_mfma_f32_16x16x32_bf16(ah1, bh, acc[1][ni], 0, 0, 0);
        }
    }
    float asv[4], adv[4];
    #pragma unroll
    for (int ni = 0; ni < 4; ni++) {
        asv[ni] = a_src[ni * 16 + lr];
        adv[ni] = a_dst[ni * 16 + lr];
    }
    #pragma unroll
    for (int mi = 0; mi < 2; mi++) {
        f32x4 ps = zf, pd = zf;
        #pragma unroll
        for (int ni = 0; ni < 4; ni++)
            #pragma unroll
            for (int r = 0; r < 4; r++) {
                ps[r] += acc[mi][ni][r] * asv[ni];
                pd[r] += acc[mi][ni][r] * adv[ni];
            }
        #pragma unroll
        for (int m = 1; m < 16; m <<= 1)
            #pragma unroll
            for (int r = 0; r < 4; r++) {
                ps[r] += __shfl_xor(ps[r], m);
                pd[r] += __shfl_xor(pd[r], m);
            }
        #pragma unroll
        for (int r = 0; r < 4; r++) {
            int n = wrow + mi * 16 + lq * 4 + r;
            if (lr == 0 && n < NN) { as2[n] = ps[r]; ad2[n] = pd[r]; }
        }
        #pragma unroll
        for (int ni = 0; ni < 4; ni++)
            #pragma unroll
            for (int r = 0; r < 4; r++) {
                int n = wrow + mi * 16 + lq * 4 + r;
                if (n < NN)
                    g2b[(size_t)n * 64 + ni * 16 + lr] = f2bf(acc[mi][ni][r]);
            }
    }
}

// ---------------- layer-1 aggregation: edge-paired dot2 gather ----------------
__global__ __launch_bounds__(256) void agg1_kernel(
        const unsigned short* __restrict__ h1b, const int* __restrict__ row_ptr,
        const int* __restrict__ csr_src, const float* __restrict__ as,
        const float* __restrict__ ad, const float* __restrict__ b1,
        unsigned short* __restrict__ h2hi, unsigned short* __restrict__ h2lo) {
    __shared__ int            ssrc[4][64];
    __shared__ unsigned short wbf[4][4][64];
    int tid = threadIdx.x;
    int wv = tid >> 6, lane = tid & 63;
    int n = blockIdx.x * 4 + wv;
    if (n >= NN) return;
    int start = row_ptr[n], end = row_ptr[n + 1];
    float4 adv = ((const float4*)ad)[n];
    int whead = lane >> 4;
    float4 acc = make_float4(0.f, 0.f, 0.f, 0.f);
    float d0 = 0.f, d1 = 0.f, d2 = 0.f, d3 = 0.f;
    for (int c0 = start; c0 < end; c0 += 64) {
        int m = min(64, end - c0);
        if (lane < m) {
            int s = csr_src[c0 + lane];
            ssrc[wv][lane] = s;
            float4 asv = ((const float4*)as)[s];
            float e0 = asv.x + adv.x; e0 = e0 > 0.f ? e0 : 0.2f * e0; float x0 = __expf(e0);
            float e1 = asv.y + adv.y; e1 = e1 > 0.f ? e1 : 0.2f * e1; float x1 = __expf(e1);
            float e2 = asv.z + adv.z; e2 = e2 > 0.f ? e2 : 0.2f * e2; float x2 = __expf(e2);
            float e3 = asv.w + adv.w; e3 = e3 > 0.f ? e3 : 0.2f * e3; float x3 = __expf(e3);
            wbf[wv][0][lane] = f2bf(x0);
            wbf[wv][1][lane] = f2bf(x1);
            wbf[wv][2][lane] = f2bf(x2);
            wbf[wv][3][lane] = f2bf(x3);
            d0 += x0; d1 += x1; d2 += x2; d3 += x3;
        }
        int j = 0;
        for (; j + 4 <= m; j += 4) {
            int s0 = ssrc[wv][j], s1 = ssrc[wv][j + 1];
            int s2 = ssrc[wv][j + 2], s3 = ssrc[wv][j + 3];
            uint2 ha = ((const uint2*)h1b)[(size_t)s0 * 64 + lane];
            uint2 hb = ((const uint2*)h1b)[(size_t)s1 * 64 + lane];
            uint2 hc = ((const uint2*)h1b)[(size_t)s2 * 64 + lane];
            uint2 hd = ((const uint2*)h1b)[(size_t)s3 * 64 + lane];
            unsigned wp01 = *(const unsigned*)&wbf[wv][whead][j];
            unsigned wp23 = *(const unsigned*)&wbf[wv][whead][j + 2];
            acc.x = fdot2bf(prm(hb.x, ha.x, 0x05040100), wp01, acc.x);
            acc.y = fdot2bf(prm(hb.x, ha.x, 0x07060302), wp01, acc.y);
            acc.z = fdot2bf(prm(hb.y, ha.y, 0x05040100), wp01, acc.z);
            acc.w = fdot2bf(prm(hb.y, ha.y, 0x07060302), wp01, acc.w);
            acc.x = fdot2bf(prm(hd.x, hc.x, 0x05040100), wp23, acc.x);
            acc.y = fdot2bf(prm(hd.x, hc.x, 0x07060302), wp23, acc.y);
            acc.z = fdot2bf(prm(hd.y, hc.y, 0x05040100), wp23, acc.z);
            acc.w = fdot2bf(prm(hd.y, hc.y, 0x07060302), wp23, acc.w);
        }
        for (; j + 2 <= m; j += 2) {
            int s0 = ssrc[wv][j], s1 = ssrc[wv][j + 1];
            uint2 ha = ((const uint2*)h1b)[(size_t)s0 * 64 + lane];
            uint2 hb = ((const uint2*)h1b)[(size_t)s1 * 64 + lane];
            unsigned wp = *(const unsigned*)&wbf[wv][whead][j];
            acc.x = fdot2bf(prm(hb.x, ha.x, 0x05040100), wp, acc.x);
            acc.y = fdot2bf(prm(hb.x, ha.x, 0x07060302), wp, acc.y);
            acc.z = fdot2bf(prm(hb.y, ha.y, 0x05040100), wp, acc.z);
            acc.w = fdot2bf(prm(hb.y, ha.y, 0x07060302), wp, acc.w);
        }
        if (j < m) {
            int s = ssrc[wv][j];
            float w = bf2f(wbf[wv][whead][j]);
            ushort4 hv = ((const ushort4*)h1b)[(size_t)s * 64 + lane];
            acc.x += bf2f(hv.x) * w; acc.y += bf2f(hv.y) * w;
            acc.z += bf2f(hv.z) * w; acc.w += bf2f(hv.w) * w;
        }
    }
    #pragma unroll
    for (int off = 32; off; off >>= 1) {
        d0 += __shfl_down(d0, off); d1 += __shfl_down(d1, off);
        d2 += __shfl_down(d2, off); d3 += __shfl_down(d3, off);
    }
    d0 = __shfl(d0, 0); d1 = __shfl(d1, 0);
    d2 = __shfl(d2, 0); d3 = __shfl(d3, 0);
    float den = whead == 0 ? d0 : whead == 1 ? d1 : whead == 2 ? d2 : d3;
    float inv = 1.f / (den + 1e-16f);
    float4 bv = ((const float4*)b1)[lane];
    float4 r;
    r.x = acc.x * inv + bv.x; r.y = acc.y * inv + bv.y;
    r.z = acc.z * inv + bv.z; r.w = acc.w * inv + bv.w;
    r.x = r.x > 0.f ? r.x : expm1f(r.x);
    r.y = r.y > 0.f ? r.y : expm1f(r.y);
    r.z = r.z > 0.f ? r.z : expm1f(r.z);
    r.w = r.w > 0.f ? r.w : expm1f(r.w);
    ushort4 hi4, lo4;
    hi4.x = f2bf(r.x); lo4.x = f2bf(r.x - bf2f(hi4.x));
    hi4.y = f2bf(r.y); lo4.y = f2bf(r.y - bf2f(hi4.y));
    hi4.z = f2bf(r.z); lo4.z = f2bf(r.z - bf2f(hi4.z));
    hi4.w = f2bf(r.w); lo4.w = f2bf(r.w - bf2f(hi4.w));
    ((ushort4*)h2hi)[(size_t)n * 64 + lane] = hi4;
    ((ushort4*)h2lo)[(size_t)n * 64 + lane] = lo4;
}

// ---------------- layer-2 aggregation: edge-paired dot2 gather ----------------
__global__ __launch_bounds__(256) void agg2_kernel(
        const unsigned short* __restrict__ g2b, const int* __restrict__ row_ptr,
        const int* __restrict__ csr_src, const float* __restrict__ as,
        const float* __restrict__ ad, const float* __restrict__ b2,
        float* __restrict__ out) {
    __shared__ int            ssrc[4][64];
    __shared__ unsigned short wbf[4][64];
    int tid = threadIdx.x;
    int wv = tid >> 6, lane = tid & 63;
    int n = blockIdx.x * 4 + wv;
    if (n >= NN) return;
    int start = row_ptr[n], end = row_ptr[n + 1];
    float adv = ad[n];
    float acc = 0.f;
    float den = 0.f;
    for (int c0 = start; c0 < end; c0 += 64) {
        int m = min(64, end - c0);
        if (lane < m) {
            int s = csr_src[c0 + lane];
            ssrc[wv][lane] = s;
            float e = as[s] + adv;
            e = e > 0.f ? e : 0.2f * e;
            float x = __expf(e);
            wbf[wv][lane] = f2bf(x);
            den += x;
        }
        int j = 0;
        for (; j + 4 <= m; j += 4) {
            int s0 = ssrc[wv][j], s1 = ssrc[wv][j + 1];
            int s2 = ssrc[wv][j + 2], s3 = ssrc[wv][j + 3];
            unsigned g0 = g2b[(size_t)s0 * 64 + lane];
            unsigned g1 = g2b[(size_t)s1 * 64 + lane];
            unsigned g2 = g2b[(size_t)s2 * 64 + lane];
            unsigned g3 = g2b[(size_t)s3 * 64 + lane];
            unsigned wp01 = *(const unsigned*)&wbf[wv][j];
            unsigned wp23 = *(const unsigned*)&wbf[wv][j + 2];
            acc = fdot2bf(prm(g1, g0, 0x05040100), wp01, acc);
            acc = fdot2bf(prm(g3, g2, 0x05040100), wp23, acc);
        }
        for (; j + 2 <= m; j += 2) {
            int s0 = ssrc[wv][j], s1 = ssrc[wv][j + 1];
            unsigned g0 = g2b[(size_t)s0 * 64 + lane];
            unsigned g1 = g2b[(size_t)s1 * 64 + lane];
            unsigned wp = *(const unsigned*)&wbf[wv][j];
            acc = fdot2bf(prm(g1, g0, 0x05040100), wp, acc);
        }
        if (j < m) {
            int s = ssrc[wv][j];
            acc += bf2f(g2b[(size_t)s * 64 + lane]) * bf2f(wbf[wv][j]);
        }
    }
    #pragma unroll
    for (int off = 32; off; off >>= 1) den += __shfl_down(den, off);
    den = __shfl(den, 0);
    float inv = 1.f / (den + 1e-16f);
    float r = acc * inv + b2[lane];
    out[(size_t)n * 64 + lane] = r > 0.f ? r : expm1f(r);
}

// ---------------- launch ----------------

extern "C" void kernel_launch(void* const* d_in, const int* in_sizes, int n_in,
                              void* d_out, int out_size, void* d_ws, size_t ws_size,
                              hipStream_t stream) {
    const float* x      = (const float*)d_in[0];
    const int*   ei     = (const int*)d_in[1];
    const float* W1     = (const float*)d_in[2];
    const float* a_src1 = (const float*)d_in[3];
    const float* a_dst1 = (const float*)d_in[4];
    const float* b1     = (const float*)d_in[5];
    const float* W2     = (const float*)d_in[6];
    const float* a_src2 = (const float*)d_in[7];
    const float* a_dst2 = (const float*)d_in[8];
    const float* b2     = (const float*)d_in[9];
    float* out = (float*)d_out;

    char* base = (char*)d_ws;
    size_t off = 0;
    auto alloc = [&](size_t bytes) -> void* {
        void* p = base + off;
        off = (off + bytes + 255) & ~(size_t)255;
        return p;
    };
    int*   deg     = (int*)alloc(NN * sizeof(int));
    int*   rank    = (int*)alloc(EE * sizeof(int));
    int*   bsum    = (int*)alloc(SCAN_BLOCKS * sizeof(int));
    int*   boff    = (int*)alloc(SCAN_BLOCKS * sizeof(int));
    int*   row_ptr = (int*)alloc((NN + 1) * sizeof(int));
    int*   csr_src = (int*)alloc(EE * sizeof(int));
    unsigned short* W1Thi = (unsigned short*)alloc(256 * 128 * 2);
    unsigned short* W1Tlo = (unsigned short*)alloc(256 * 128 * 2);
    unsigned short* W2Thi = (unsigned short*)alloc(64 * 256 * 2);
    unsigned short* W2Tlo = (unsigned short*)alloc(64 * 256 * 2);
    unsigned short* h1b   = (unsigned short*)alloc((size_t)NN * 256 * 2);
    float* as1     = (float*)alloc((size_t)NN * 4 * sizeof(float));
    float* ad1     = (float*)alloc((size_t)NN * 4 * sizeof(float));
    unsigned short* h2hi  = (unsigned short*)alloc((size_t)NN * 256 * 2);
    unsigned short* h2lo  = (unsigned short*)alloc((size_t)NN * 256 * 2);
    unsigned short* g2b   = (unsigned short*)alloc((size_t)NN * 64 * 2);
    float* as2     = (float*)alloc((size_t)NN * sizeof(float));
    float* ad2     = (float*)alloc((size_t)NN * sizeof(float));

    hipMemsetAsync(deg, 0, NN * sizeof(int), stream);

    front_kernel<<<EBLOCKS + 128 + 64, 256, 0, stream>>>(ei, deg, rank, W1, W1Thi, W1Tlo,
                                                         W2, W2Thi, W2Tlo);
    deg_partial_kernel<<<SCAN_BLOCKS, 256, 0, stream>>>(deg, bsum);
    scanb_kernel<<<1, 256, 0, stream>>>(bsum, boff, row_ptr);
    fill_kernel<<<SCAN_BLOCKS, 256, 0, stream>>>(deg, boff, row_ptr);
    scatter_kernel<<<EBLOCKS, 256, 0, stream>>>(ei, rank, row_ptr, csr_src);

    gemm1_mfma<<<(NN + 31) / 32, 256, 0, stream>>>(x, W1Thi, W1Tlo,
                                                   a_src1, a_dst1, h1b, as1, ad1);
    agg1_kernel<<<(NN + 3) / 4, 256, 0, stream>>>(h1b, row_ptr, csr_src, as1, ad1, b1,
                                                  h2hi, h2lo);
    gemm2_mfma<<<(NN + 127) / 128, 256, 0, stream>>>(h2hi, h2lo, W2Thi, W2Tlo,
                                                     a_src2, a_dst2, g2b, as2, ad2);
    agg2_kernel<<<(NN + 3) / 4, 256, 0, stream>>>(g2b, row_ptr, csr_src, as2, ad2, b2, out);
}

// Round 8
// 287.680 us; speedup vs baseline: 1.1906x; 1.0147x over previous
//
#include <hip/hip_runtime.h>
#include <math.h>

#define NN 50000
#define EE 800000
#define IN_C 128
#define HID 64
#define HEADS 4
#define SCAN_BLOCKS ((NN + 255) / 256)   // 196
#define EBLOCKS ((EE + 255) / 256)       // 3125

typedef __attribute__((ext_vector_type(8))) short bf16x8;
typedef __attribute__((ext_vector_type(4))) float f32x4;

#if defined(__has_builtin)
#if __has_builtin(__builtin_amdgcn_fdot2_f32_bf16)
#define HAVE_FDOT2_BF16 1
#endif
#endif

// ---------------- helpers ----------------

__device__ inline unsigned short f2bf(float f) {       // fp32 -> bf16 RNE
    unsigned u = __float_as_uint(f);
    return (unsigned short)((u + 0x7fff + ((u >> 16) & 1)) >> 16);
}
__device__ inline float bf2f(unsigned short s) {
    return __uint_as_float(((unsigned)s) << 16);
}
__device__ inline unsigned prm(unsigned a, unsigned b, unsigned sel) {
    return __builtin_amdgcn_perm(a, b, sel);
}
#ifdef HAVE_FDOT2_BF16
typedef __attribute__((ext_vector_type(2))) __bf16 bf2v;
__device__ inline float fdot2bf(unsigned h, unsigned w, float acc) {
    return __builtin_amdgcn_fdot2_f32_bf16(__builtin_bit_cast(bf2v, h),
                                           __builtin_bit_cast(bf2v, w), acc, false);
}
#else
__device__ inline float fdot2bf(unsigned h, unsigned w, float acc) {
    return acc + bf2f((unsigned short)(h & 0xffff)) * bf2f((unsigned short)(w & 0xffff))
               + bf2f((unsigned short)(h >> 16)) * bf2f((unsigned short)(w >> 16));
}
#endif

__device__ inline int wave_incl_scan(int v, int lane) {
    #pragma unroll
    for (int off = 1; off < 64; off <<= 1) {
        int t = __shfl_up(v, off);
        if (lane >= off) v += t;
    }
    return v;
}

__device__ inline int block256_excl_scan(int v, int tid, int* ws4) {
    int lane = tid & 63, wv = tid >> 6;
    int incl = wave_incl_scan(v, lane);
    if (lane == 63) ws4[wv] = incl;
    __syncthreads();
    if (tid == 0) {
        int run = 0;
        #pragma unroll
        for (int i = 0; i < 4; i++) { int t = ws4[i]; ws4[i] = run; run += t; }
    }
    __syncthreads();
    return incl + ws4[wv] - v;
}

// ---------------- front: degree histogram (+edge ranks) + weight splits ----------------

__global__ void front_kernel(const int* __restrict__ ei, int* __restrict__ deg,
                             int* __restrict__ rank,
                             const float* __restrict__ W1, unsigned short* __restrict__ W1Thi,
                             unsigned short* __restrict__ W1Tlo,
                             const float* __restrict__ W2, unsigned short* __restrict__ W2Thi,
                             unsigned short* __restrict__ W2Tlo) {
    int b = blockIdx.x;
    int tid = threadIdx.x;
    if (b < EBLOCKS) {
        int i = b * 256 + tid;
        if (i < EE) rank[i] = atomicAdd(&deg[ei[EE + i]], 1);
    } else if (b < EBLOCKS + 128) {
        int idx = (b - EBLOCKS) * 256 + tid;         // W1 [128][256]
        int r = idx >> 8, c = idx & 255;
        float v = W1[idx];
        unsigned short h = f2bf(v);
        W1Thi[c * 128 + r] = h;
        W1Tlo[c * 128 + r] = f2bf(v - bf2f(h));
    } else {
        int idx = (b - EBLOCKS - 128) * 256 + tid;   // W2 [256][64]
        int r = idx >> 6, c = idx & 63;
        float v = W2[idx];
        unsigned short h = f2bf(v);
        W2Thi[c * 256 + r] = h;
        W2Tlo[c * 256 + r] = f2bf(v - bf2f(h));
    }
}

// ---------------- single-pass CSR scan (decoupled lookback) ----------------
// desc[b]: (flag=1 in high 32) | block aggregate (low 32). Pre-zeroed by memset.
// 196 blocks are trivially co-resident -> spin on predecessors is deadlock-free.
__global__ void scan_fill_kernel(const int* __restrict__ deg,
                                 unsigned long long* __restrict__ desc,
                                 int* __restrict__ row_ptr) {
    __shared__ int ws4[4];
    __shared__ int sbase;
    int b = blockIdx.x, tid = threadIdx.x;
    int idx = b * 256 + tid;
    int d = (idx < NN) ? deg[idx] : 0;
    int excl = block256_excl_scan(d, tid, ws4);
    if (tid == 255) {
        unsigned total = (unsigned)(excl + d);
        __threadfence();
        atomicExch(&desc[b], (1ULL << 32) | (unsigned long long)total);
    }
    if (tid < 64) {
        int sum = 0;
        int hi = b;
        while (hi > 0) {
            int lo = hi - 64; if (lo < 0) lo = 0;
            int myi = lo + tid;
            unsigned v = 0;
            if (myi < hi) {
                unsigned long long d8;
                do { d8 = atomicAdd(&desc[myi], 0ULL); } while ((d8 >> 32) == 0);
                v = (unsigned)(d8 & 0xffffffffULL);
            }
            #pragma unroll
            for (int off = 32; off; off >>= 1) v += __shfl_down(v, off);
            v = __shfl(v, 0);
            sum += (int)v;
            hi = lo;
        }
        if (tid == 0) sbase = sum;
    }
    __syncthreads();
    int gbase = sbase;
    if (idx < NN) row_ptr[idx] = gbase + excl;
    if (b == gridDim.x - 1 && tid == 255) row_ptr[NN] = gbase + excl + d;  // == EE
}

// atomic-free scatter: position = row_ptr[dst] + precomputed rank
__global__ void scatter_kernel(const int* __restrict__ ei, const int* __restrict__ rank,
                               const int* __restrict__ row_ptr, int* __restrict__ csr_src) {
    int i = blockIdx.x * blockDim.x + threadIdx.x;
    if (i < EE) {
        int d = ei[EE + i];
        csr_src[row_ptr[d] + rank[i]] = ei[i];
    }
}

// ---------------- layer-1 MFMA GEMM + fused alpha ----------------
// h1 = x @ W1 (50000x128 @ 128x256). 64 rows/block (amortize W1T reads).
__global__ __launch_bounds__(256) void gemm1_mfma(
        const float* __restrict__ x,
        const unsigned short* __restrict__ Bhi, const unsigned short* __restrict__ Blo,
        const float* __restrict__ a_src, const float* __restrict__ a_dst,
        unsigned short* __restrict__ h1b, float* __restrict__ as1, float* __restrict__ ad1) {
    __shared__ unsigned short Ahi[64][136];   // +8 pad
    __shared__ unsigned short Alo[64][136];
    int tid = threadIdx.x;
    int w = tid >> 6, lane = tid & 63;
    int lq = lane >> 4, lr = lane & 15;
    int brow = blockIdx.x * 64;
    // stage 64 rows x 128 cols of x -> bf16 hi/lo in LDS
    {
        int row = tid >> 2;                    // 0..63
        int col0 = (tid & 3) * 32;             // 0,32,64,96
        int gr = min(brow + row, NN - 1);
        #pragma unroll
        for (int i = 0; i < 32; i += 4) {
            float4 v = *(const float4*)(x + (size_t)gr * 128 + col0 + i);
            unsigned short h0 = f2bf(v.x), h1 = f2bf(v.y), h2 = f2bf(v.z), h3 = f2bf(v.w);
            Ahi[row][col0 + i + 0] = h0; Alo[row][col0 + i + 0] = f2bf(v.x - bf2f(h0));
            Ahi[row][col0 + i + 1] = h1; Alo[row][col0 + i + 1] = f2bf(v.y - bf2f(h1));
            Ahi[row][col0 + i + 2] = h2; Alo[row][col0 + i + 2] = f2bf(v.z - bf2f(h2));
            Ahi[row][col0 + i + 3] = h3; Alo[row][col0 + i + 3] = f2bf(v.w - bf2f(h3));
        }
    }
    __syncthreads();
    f32x4 acc[4][4];
    f32x4 zf = {0.f, 0.f, 0.f, 0.f};
    #pragma unroll
    for (int mi = 0; mi < 4; mi++)
        #pragma unroll
        for (int ni = 0; ni < 4; ni++) acc[mi][ni] = zf;
    #pragma unroll
    for (int q = 0; q < 4; q++) {             // K = 128 = 4 chunks of 32
        int ko = q * 32 + lq * 8;
        bf16x8 ah[4], al[4];
        #pragma unroll
        for (int mi = 0; mi < 4; mi++) {
            ah[mi] = *(const bf16x8*)(const void*)&Ahi[mi * 16 + lr][ko];
            al[mi] = *(const bf16x8*)(const void*)&Alo[mi * 16 + lr][ko];
        }
        #pragma unroll
        for (int ni = 0; ni < 4; ni++) {
            size_t bo = (size_t)(w * 64 + ni * 16 + lr) * 128 + ko;
            bf16x8 bh = *(const bf16x8*)(const void*)(Bhi + bo);
            bf16x8 bl = *(const bf16x8*)(const void*)(Blo + bo);
            #pragma unroll
            for (int mi = 0; mi < 4; mi++) {
                acc[mi][ni] = __builtin_amdgcn_mfma_f32_16x16x32_bf16(al[mi], bh, acc[mi][ni], 0, 0, 0);
                acc[mi][ni] = __builtin_amdgcn_mfma_f32_16x16x32_bf16(ah[mi], bl, acc[mi][ni], 0, 0, 0);
                acc[mi][ni] = __builtin_amdgcn_mfma_f32_16x16x32_bf16(ah[mi], bh, acc[mi][ni], 0, 0, 0);
            }
        }
    }
    float asv[4], adv[4];
    #pragma unroll
    for (int ni = 0; ni < 4; ni++) {
        asv[ni] = a_src[w * 64 + ni * 16 + lr];
        adv[ni] = a_dst[w * 64 + ni * 16 + lr];
    }
    #pragma unroll
    for (int mi = 0; mi < 4; mi++) {
        f32x4 ps = zf, pd = zf;
        #pragma unroll
        for (int ni = 0; ni < 4; ni++)
            #pragma unroll
            for (int r = 0; r < 4; r++) {
                ps[r] += acc[mi][ni][r] * asv[ni];
                pd[r] += acc[mi][ni][r] * adv[ni];
            }
        #pragma unroll
        for (int m = 1; m < 16; m <<= 1)
            #pragma unroll
            for (int r = 0; r < 4; r++) {
                ps[r] += __shfl_xor(ps[r], m);
                pd[r] += __shfl_xor(pd[r], m);
            }
        #pragma unroll
        for (int r = 0; r < 4; r++) {
            int n = brow + mi * 16 + lq * 4 + r;
            if (lr == 0 && n < NN) { as1[n * 4 + w] = ps[r]; ad1[n * 4 + w] = pd[r]; }
        }
        #pragma unroll
        for (int ni = 0; ni < 4; ni++)
            #pragma unroll
            for (int r = 0; r < 4; r++) {
                int n = brow + mi * 16 + lq * 4 + r;
                if (n < NN)
                    h1b[(size_t)n * 256 + w * 64 + ni * 16 + lr] = f2bf(acc[mi][ni][r]);
            }
    }
}

// ---------------- layer-2 MFMA GEMM + fused alpha (single-bf16 A) ----------------
__global__ __launch_bounds__(256) void gemm2_mfma(
        const unsigned short* __restrict__ Ab,
        const unsigned short* __restrict__ Bhi, const unsigned short* __restrict__ Blo,
        const float* __restrict__ a_src, const float* __restrict__ a_dst,
        unsigned short* __restrict__ g2b, float* __restrict__ as2, float* __restrict__ ad2) {
    int tid = threadIdx.x;
    int w = tid >> 6, lane = tid & 63;
    int lq = lane >> 4, lr = lane & 15;
    int wrow = blockIdx.x * 128 + w * 32;
    f32x4 acc[2][4];
    f32x4 zf = {0.f, 0.f, 0.f, 0.f};
    #pragma unroll
    for (int mi = 0; mi < 2; mi++)
        #pragma unroll
        for (int ni = 0; ni < 4; ni++) acc[mi][ni] = zf;
    int ra = min(wrow + lr, NN - 1);
    int rb = min(wrow + 16 + lr, NN - 1);
    #pragma unroll
    for (int q = 0; q < 8; q++) {             // K = 256 = 8 chunks of 32
        int ko = q * 32 + lq * 8;
        bf16x8 ah0 = *(const bf16x8*)(const void*)(Ab + (size_t)ra * 256 + ko);
        bf16x8 ah1 = *(const bf16x8*)(const void*)(Ab + (size_t)rb * 256 + ko);
        #pragma unroll
        for (int ni = 0; ni < 4; ni++) {
            size_t bo = (size_t)(ni * 16 + lr) * 256 + ko;
            bf16x8 bh = *(const bf16x8*)(const void*)(Bhi + bo);
            bf16x8 bl = *(const bf16x8*)(const void*)(Blo + bo);
            acc[0][ni] = __builtin_amdgcn_mfma_f32_16x16x32_bf16(ah0, bl, acc[0][ni], 0, 0, 0);
            acc[0][ni] = __builtin_amdgcn_mfma_f32_16x16x32_bf16(ah0, bh, acc[0][ni], 0, 0, 0);
            acc[1][ni] = __builtin_amdgcn_mfma_f32_16x16x32_bf16(ah1, bl, acc[1][ni], 0, 0, 0);
            acc[1][ni] = __builtin_amdgcn_mfma_f32_16x16x32_bf16(ah1, bh, acc[1][ni], 0, 0, 0);
        }
    }
    float asv[4], adv[4];
    #pragma unroll
    for (int ni = 0; ni < 4; ni++) {
        asv[ni] = a_src[ni * 16 + lr];
        adv[ni] = a_dst[ni * 16 + lr];
    }
    #pragma unroll
    for (int mi = 0; mi < 2; mi++) {
        f32x4 ps = zf, pd = zf;
        #pragma unroll
        for (int ni = 0; ni < 4; ni++)
            #pragma unroll
            for (int r = 0; r < 4; r++) {
                ps[r] += acc[mi][ni][r] * asv[ni];
                pd[r] += acc[mi][ni][r] * adv[ni];
            }
        #pragma unroll
        for (int m = 1; m < 16; m <<= 1)
            #pragma unroll
            for (int r = 0; r < 4; r++) {
                ps[r] += __shfl_xor(ps[r], m);
                pd[r] += __shfl_xor(pd[r], m);
            }
        #pragma unroll
        for (int r = 0; r < 4; r++) {
            int n = wrow + mi * 16 + lq * 4 + r;
            if (lr == 0 && n < NN) { as2[n] = ps[r]; ad2[n] = pd[r]; }
        }
        #pragma unroll
        for (int ni = 0; ni < 4; ni++)
            #pragma unroll
            for (int r = 0; r < 4; r++) {
                int n = wrow + mi * 16 + lq * 4 + r;
                if (n < NN)
                    g2b[(size_t)n * 64 + ni * 16 + lr] = f2bf(acc[mi][ni][r]);
            }
    }
}

// ---------------- layer-1 aggregation: edge-paired dot2 gather ----------------
__global__ __launch_bounds__(256) void agg1_kernel(
        const unsigned short* __restrict__ h1b, const int* __restrict__ row_ptr,
        const int* __restrict__ csr_src, const float* __restrict__ as,
        const float* __restrict__ ad, const float* __restrict__ b1,
        unsigned short* __restrict__ h2b) {
    __shared__ int            ssrc[4][64];
    __shared__ unsigned short wbf[4][4][64];
    int tid = threadIdx.x;
    int wv = tid >> 6, lane = tid & 63;
    int n = blockIdx.x * 4 + wv;
    if (n >= NN) return;
    int start = row_ptr[n], end = row_ptr[n + 1];
    float4 adv = ((const float4*)ad)[n];
    int whead = lane >> 4;
    float4 acc = make_float4(0.f, 0.f, 0.f, 0.f);
    float d0 = 0.f, d1 = 0.f, d2 = 0.f, d3 = 0.f;
    for (int c0 = start; c0 < end; c0 += 64) {
        int m = min(64, end - c0);
        if (lane < m) {
            int s = csr_src[c0 + lane];
            ssrc[wv][lane] = s;
            float4 asv = ((const float4*)as)[s];
            float e0 = asv.x + adv.x; e0 = e0 > 0.f ? e0 : 0.2f * e0; float x0 = __expf(e0);
            float e1 = asv.y + adv.y; e1 = e1 > 0.f ? e1 : 0.2f * e1; float x1 = __expf(e1);
            float e2 = asv.z + adv.z; e2 = e2 > 0.f ? e2 : 0.2f * e2; float x2 = __expf(e2);
            float e3 = asv.w + adv.w; e3 = e3 > 0.f ? e3 : 0.2f * e3; float x3 = __expf(e3);
            wbf[wv][0][lane] = f2bf(x0);
            wbf[wv][1][lane] = f2bf(x1);
            wbf[wv][2][lane] = f2bf(x2);
            wbf[wv][3][lane] = f2bf(x3);
            d0 += x0; d1 += x1; d2 += x2; d3 += x3;
        }
        int j = 0;
        for (; j + 4 <= m; j += 4) {
            int s0 = ssrc[wv][j], s1 = ssrc[wv][j + 1];
            int s2 = ssrc[wv][j + 2], s3 = ssrc[wv][j + 3];
            uint2 ha = ((const uint2*)h1b)[(size_t)s0 * 64 + lane];
            uint2 hb = ((const uint2*)h1b)[(size_t)s1 * 64 + lane];
            uint2 hc = ((const uint2*)h1b)[(size_t)s2 * 64 + lane];
            uint2 hd = ((const uint2*)h1b)[(size_t)s3 * 64 + lane];
            unsigned wp01 = *(const unsigned*)&wbf[wv][whead][j];
            unsigned wp23 = *(const unsigned*)&wbf[wv][whead][j + 2];
            acc.x = fdot2bf(prm(hb.x, ha.x, 0x05040100), wp01, acc.x);
            acc.y = fdot2bf(prm(hb.x, ha.x, 0x07060302), wp01, acc.y);
            acc.z = fdot2bf(prm(hb.y, ha.y, 0x05040100), wp01, acc.z);
            acc.w = fdot2bf(prm(hb.y, ha.y, 0x07060302), wp01, acc.w);
            acc.x = fdot2bf(prm(hd.x, hc.x, 0x05040100), wp23, acc.x);
            acc.y = fdot2bf(prm(hd.x, hc.x, 0x07060302), wp23, acc.y);
            acc.z = fdot2bf(prm(hd.y, hc.y, 0x05040100), wp23, acc.z);
            acc.w = fdot2bf(prm(hd.y, hc.y, 0x07060302), wp23, acc.w);
        }
        for (; j + 2 <= m; j += 2) {
            int s0 = ssrc[wv][j], s1 = ssrc[wv][j + 1];
            uint2 ha = ((const uint2*)h1b)[(size_t)s0 * 64 + lane];
            uint2 hb = ((const uint2*)h1b)[(size_t)s1 * 64 + lane];
            unsigned wp = *(const unsigned*)&wbf[wv][whead][j];
            acc.x = fdot2bf(prm(hb.x, ha.x, 0x05040100), wp, acc.x);
            acc.y = fdot2bf(prm(hb.x, ha.x, 0x07060302), wp, acc.y);
            acc.z = fdot2bf(prm(hb.y, ha.y, 0x05040100), wp, acc.z);
            acc.w = fdot2bf(prm(hb.y, ha.y, 0x07060302), wp, acc.w);
        }
        if (j < m) {
            int s = ssrc[wv][j];
            float w = bf2f(wbf[wv][whead][j]);
            ushort4 hv = ((const ushort4*)h1b)[(size_t)s * 64 + lane];
            acc.x += bf2f(hv.x) * w; acc.y += bf2f(hv.y) * w;
            acc.z += bf2f(hv.z) * w; acc.w += bf2f(hv.w) * w;
        }
    }
    #pragma unroll
    for (int off = 32; off; off >>= 1) {
        d0 += __shfl_down(d0, off); d1 += __shfl_down(d1, off);
        d2 += __shfl_down(d2, off); d3 += __shfl_down(d3, off);
    }
    d0 = __shfl(d0, 0); d1 = __shfl(d1, 0);
    d2 = __shfl(d2, 0); d3 = __shfl(d3, 0);
    float den = whead == 0 ? d0 : whead == 1 ? d1 : whead == 2 ? d2 : d3;
    float inv = 1.f / (den + 1e-16f);
    float4 bv = ((const float4*)b1)[lane];
    float4 r;
    r.x = acc.x * inv + bv.x; r.y = acc.y * inv + bv.y;
    r.z = acc.z * inv + bv.z; r.w = acc.w * inv + bv.w;
    r.x = r.x > 0.f ? r.x : expm1f(r.x);
    r.y = r.y > 0.f ? r.y : expm1f(r.y);
    r.z = r.z > 0.f ? r.z : expm1f(r.z);
    r.w = r.w > 0.f ? r.w : expm1f(r.w);
    ushort4 hv;
    hv.x = f2bf(r.x); hv.y = f2bf(r.y); hv.z = f2bf(r.z); hv.w = f2bf(r.w);
    ((ushort4*)h2b)[(size_t)n * 64 + lane] = hv;
}

// ---------------- layer-2 aggregation: edge-paired dot2 gather ----------------
__global__ __launch_bounds__(256) void agg2_kernel(
        const unsigned short* __restrict__ g2b, const int* __restrict__ row_ptr,
        const int* __restrict__ csr_src, const float* __restrict__ as,
        const float* __restrict__ ad, const float* __restrict__ b2,
        float* __restrict__ out) {
    __shared__ int            ssrc[4][64];
    __shared__ unsigned short wbf[4][64];
    int tid = threadIdx.x;
    int wv = tid >> 6, lane = tid & 63;
    int n = blockIdx.x * 4 + wv;
    if (n >= NN) return;
    int start = row_ptr[n], end = row_ptr[n + 1];
    float adv = ad[n];
    float acc = 0.f;
    float den = 0.f;
    for (int c0 = start; c0 < end; c0 += 64) {
        int m = min(64, end - c0);
        if (lane < m) {
            int s = csr_src[c0 + lane];
            ssrc[wv][lane] = s;
            float e = as[s] + adv;
            e = e > 0.f ? e : 0.2f * e;
            float x = __expf(e);
            wbf[wv][lane] = f2bf(x);
            den += x;
        }
        int j = 0;
        for (; j + 4 <= m; j += 4) {
            int s0 = ssrc[wv][j], s1 = ssrc[wv][j + 1];
            int s2 = ssrc[wv][j + 2], s3 = ssrc[wv][j + 3];
            unsigned g0 = g2b[(size_t)s0 * 64 + lane];
            unsigned g1 = g2b[(size_t)s1 * 64 + lane];
            unsigned g2 = g2b[(size_t)s2 * 64 + lane];
            unsigned g3 = g2b[(size_t)s3 * 64 + lane];
            unsigned wp01 = *(const unsigned*)&wbf[wv][j];
            unsigned wp23 = *(const unsigned*)&wbf[wv][j + 2];
            acc = fdot2bf(prm(g1, g0, 0x05040100), wp01, acc);
            acc = fdot2bf(prm(g3, g2, 0x05040100), wp23, acc);
        }
        for (; j + 2 <= m; j += 2) {
            int s0 = ssrc[wv][j], s1 = ssrc[wv][j + 1];
            unsigned g0 = g2b[(size_t)s0 * 64 + lane];
            unsigned g1 = g2b[(size_t)s1 * 64 + lane];
            unsigned wp = *(const unsigned*)&wbf[wv][j];
            acc = fdot2bf(prm(g1, g0, 0x05040100), wp, acc);
        }
        if (j < m) {
            int s = ssrc[wv][j];
            acc += bf2f(g2b[(size_t)s * 64 + lane]) * bf2f(wbf[wv][j]);
        }
    }
    #pragma unroll
    for (int off = 32; off; off >>= 1) den += __shfl_down(den, off);
    den = __shfl(den, 0);
    float inv = 1.f / (den + 1e-16f);
    float r = acc * inv + b2[lane];
    out[(size_t)n * 64 + lane] = r > 0.f ? r : expm1f(r);
}

// ---------------- launch ----------------

extern "C" void kernel_launch(void* const* d_in, const int* in_sizes, int n_in,
                              void* d_out, int out_size, void* d_ws, size_t ws_size,
                              hipStream_t stream) {
    const float* x      = (const float*)d_in[0];
    const int*   ei     = (const int*)d_in[1];
    const float* W1     = (const float*)d_in[2];
    const float* a_src1 = (const float*)d_in[3];
    const float* a_dst1 = (const float*)d_in[4];
    const float* b1     = (const float*)d_in[5];
    const float* W2     = (const float*)d_in[6];
    const float* a_src2 = (const float*)d_in[7];
    const float* a_dst2 = (const float*)d_in[8];
    const float* b2     = (const float*)d_in[9];
    float* out = (float*)d_out;

    char* base = (char*)d_ws;
    size_t off = 0;
    auto alloc = [&](size_t bytes) -> void* {
        void* p = base + off;
        off = (off + bytes + 255) & ~(size_t)255;
        return p;
    };
    int*   deg     = (int*)alloc(NN * sizeof(int));
    unsigned long long* desc = (unsigned long long*)alloc(SCAN_BLOCKS * sizeof(unsigned long long));
    int*   rank    = (int*)alloc(EE * sizeof(int));
    int*   row_ptr = (int*)alloc((NN + 1) * sizeof(int));
    int*   csr_src = (int*)alloc(EE * sizeof(int));
    unsigned short* W1Thi = (unsigned short*)alloc(256 * 128 * 2);
    unsigned short* W1Tlo = (unsigned short*)alloc(256 * 128 * 2);
    unsigned short* W2Thi = (unsigned short*)alloc(64 * 256 * 2);
    unsigned short* W2Tlo = (unsigned short*)alloc(64 * 256 * 2);
    unsigned short* h1b   = (unsigned short*)alloc((size_t)NN * 256 * 2);
    float* as1     = (float*)alloc((size_t)NN * 4 * sizeof(float));
    float* ad1     = (float*)alloc((size_t)NN * 4 * sizeof(float));
    unsigned short* h2b   = (unsigned short*)alloc((size_t)NN * 256 * 2);
    unsigned short* g2b   = (unsigned short*)alloc((size_t)NN * 64 * 2);
    float* as2     = (float*)alloc((size_t)NN * sizeof(float));
    float* ad2     = (float*)alloc((size_t)NN * sizeof(float));

    // deg and desc are contiguous in the workspace -> one memset clears both
    size_t clear_bytes = (size_t)((char*)(desc + SCAN_BLOCKS) - (char*)deg);
    hipMemsetAsync(deg, 0, clear_bytes, stream);

    front_kernel<<<EBLOCKS + 128 + 64, 256, 0, stream>>>(ei, deg, rank, W1, W1Thi, W1Tlo,
                                                         W2, W2Thi, W2Tlo);
    scan_fill_kernel<<<SCAN_BLOCKS, 256, 0, stream>>>(deg, desc, row_ptr);
    scatter_kernel<<<EBLOCKS, 256, 0, stream>>>(ei, rank, row_ptr, csr_src);

    gemm1_mfma<<<(NN + 63) / 64, 256, 0, stream>>>(x, W1Thi, W1Tlo,
                                                   a_src1, a_dst1, h1b, as1, ad1);
    agg1_kernel<<<(NN + 3) / 4, 256, 0, stream>>>(h1b, row_ptr, csr_src, as1, ad1, b1, h2b);
    gemm2_mfma<<<(NN + 127) / 128, 256, 0, stream>>>(h2b, W2Thi, W2Tlo,
                                                     a_src2, a_dst2, g2b, as2, ad2);
    agg2_kernel<<<(NN + 3) / 4, 256, 0, stream>>>(g2b, row_ptr, csr_src, as2, ad2, b2, out);
}

// Round 9
// 284.210 us; speedup vs baseline: 1.2052x; 1.0122x over previous
//
#include <hip/hip_runtime.h>
#include <math.h>

#define NN 50000
#define EE 800000
#define IN_C 128
#define HID 64
#define HEADS 4
#define SCAN_BLOCKS ((NN + 255) / 256)   // 196
#define EBLOCKS ((EE + 255) / 256)       // 3125

typedef __attribute__((ext_vector_type(8))) short bf16x8;
typedef __attribute__((ext_vector_type(4))) float f32x4;

#if defined(__has_builtin)
#if __has_builtin(__builtin_amdgcn_fdot2_f32_bf16)
#define HAVE_FDOT2_BF16 1
#endif
#endif

// ---------------- helpers ----------------

__device__ inline unsigned short f2bf(float f) {       // fp32 -> bf16 RNE
    unsigned u = __float_as_uint(f);
    return (unsigned short)((u + 0x7fff + ((u >> 16) & 1)) >> 16);
}
__device__ inline float bf2f(unsigned short s) {
    return __uint_as_float(((unsigned)s) << 16);
}
__device__ inline unsigned prm(unsigned a, unsigned b, unsigned sel) {
    return __builtin_amdgcn_perm(a, b, sel);
}
#ifdef HAVE_FDOT2_BF16
typedef __attribute__((ext_vector_type(2))) __bf16 bf2v;
__device__ inline float fdot2bf(unsigned h, unsigned w, float acc) {
    return __builtin_amdgcn_fdot2_f32_bf16(__builtin_bit_cast(bf2v, h),
                                           __builtin_bit_cast(bf2v, w), acc, false);
}
#else
__device__ inline float fdot2bf(unsigned h, unsigned w, float acc) {
    return acc + bf2f((unsigned short)(h & 0xffff)) * bf2f((unsigned short)(w & 0xffff))
               + bf2f((unsigned short)(h >> 16)) * bf2f((unsigned short)(w >> 16));
}
#endif

__device__ inline int wave_incl_scan(int v, int lane) {
    #pragma unroll
    for (int off = 1; off < 64; off <<= 1) {
        int t = __shfl_up(v, off);
        if (lane >= off) v += t;
    }
    return v;
}

__device__ inline int block256_excl_scan(int v, int tid, int* ws4) {
    int lane = tid & 63, wv = tid >> 6;
    int incl = wave_incl_scan(v, lane);
    if (lane == 63) ws4[wv] = incl;
    __syncthreads();
    if (tid == 0) {
        int run = 0;
        #pragma unroll
        for (int i = 0; i < 4; i++) { int t = ws4[i]; ws4[i] = run; run += t; }
    }
    __syncthreads();
    return incl + ws4[wv] - v;
}

// ---------------- front: degree histogram (+edge ranks) + weight splits ----------------

__global__ void front_kernel(const int* __restrict__ ei, int* __restrict__ deg,
                             unsigned short* __restrict__ rank,
                             const float* __restrict__ W1, unsigned short* __restrict__ W1Thi,
                             unsigned short* __restrict__ W1Tlo,
                             const float* __restrict__ W2, unsigned short* __restrict__ W2Thi,
                             unsigned short* __restrict__ W2Tlo) {
    int b = blockIdx.x;
    int tid = threadIdx.x;
    if (b < EBLOCKS) {
        int i = b * 256 + tid;
        if (i < EE) rank[i] = (unsigned short)atomicAdd(&deg[ei[EE + i]], 1);
    } else if (b < EBLOCKS + 128) {
        int idx = (b - EBLOCKS) * 256 + tid;         // W1 [128][256]
        int r = idx >> 8, c = idx & 255;
        float v = W1[idx];
        unsigned short h = f2bf(v);
        W1Thi[c * 128 + r] = h;
        W1Tlo[c * 128 + r] = f2bf(v - bf2f(h));
    } else {
        int idx = (b - EBLOCKS - 128) * 256 + tid;   // W2 [256][64]
        int r = idx >> 6, c = idx & 63;
        float v = W2[idx];
        unsigned short h = f2bf(v);
        W2Thi[c * 256 + r] = h;
        W2Tlo[c * 256 + r] = f2bf(v - bf2f(h));
    }
}

// ---------------- single-pass CSR scan (decoupled lookback) ----------------
__global__ void scan_fill_kernel(const int* __restrict__ deg,
                                 unsigned long long* __restrict__ desc,
                                 int* __restrict__ row_ptr) {
    __shared__ int ws4[4];
    __shared__ int sbase;
    int b = blockIdx.x, tid = threadIdx.x;
    int idx = b * 256 + tid;
    int d = (idx < NN) ? deg[idx] : 0;
    int excl = block256_excl_scan(d, tid, ws4);
    if (tid == 255) {
        unsigned total = (unsigned)(excl + d);
        __threadfence();
        atomicExch(&desc[b], (1ULL << 32) | (unsigned long long)total);
    }
    if (tid < 64) {
        int sum = 0;
        int hi = b;
        while (hi > 0) {
            int lo = hi - 64; if (lo < 0) lo = 0;
            int myi = lo + tid;
            unsigned v = 0;
            if (myi < hi) {
                unsigned long long d8;
                do { d8 = atomicAdd(&desc[myi], 0ULL); } while ((d8 >> 32) == 0);
                v = (unsigned)(d8 & 0xffffffffULL);
            }
            #pragma unroll
            for (int off = 32; off; off >>= 1) v += __shfl_down(v, off);
            v = __shfl(v, 0);
            sum += (int)v;
            hi = lo;
        }
        if (tid == 0) sbase = sum;
    }
    __syncthreads();
    int gbase = sbase;
    if (idx < NN) row_ptr[idx] = gbase + excl;
    if (b == gridDim.x - 1 && tid == 255) row_ptr[NN] = gbase + excl + d;  // == EE
}

// atomic-free scatter: position = row_ptr[dst] + precomputed rank (u16 ids)
__global__ void scatter_kernel(const int* __restrict__ ei, const unsigned short* __restrict__ rank,
                               const int* __restrict__ row_ptr, unsigned short* __restrict__ csr_src) {
    int i = blockIdx.x * blockDim.x + threadIdx.x;
    if (i < EE) {
        int d = ei[EE + i];
        csr_src[row_ptr[d] + (int)rank[i]] = (unsigned short)ei[i];
    }
}

// ---------------- layer-1 MFMA GEMM + fused alpha ----------------
__global__ __launch_bounds__(256) void gemm1_mfma(
        const float* __restrict__ x,
        const unsigned short* __restrict__ Bhi, const unsigned short* __restrict__ Blo,
        const float* __restrict__ a_src, const float* __restrict__ a_dst,
        unsigned short* __restrict__ h1b, float* __restrict__ as1, float* __restrict__ ad1) {
    __shared__ unsigned short Ahi[64][136];   // +8 pad
    __shared__ unsigned short Alo[64][136];
    int tid = threadIdx.x;
    int w = tid >> 6, lane = tid & 63;
    int lq = lane >> 4, lr = lane & 15;
    int brow = blockIdx.x * 64;
    {
        int row = tid >> 2;                    // 0..63
        int col0 = (tid & 3) * 32;             // 0,32,64,96
        int gr = min(brow + row, NN - 1);
        #pragma unroll
        for (int i = 0; i < 32; i += 4) {
            float4 v = *(const float4*)(x + (size_t)gr * 128 + col0 + i);
            unsigned short h0 = f2bf(v.x), h1 = f2bf(v.y), h2 = f2bf(v.z), h3 = f2bf(v.w);
            Ahi[row][col0 + i + 0] = h0; Alo[row][col0 + i + 0] = f2bf(v.x - bf2f(h0));
            Ahi[row][col0 + i + 1] = h1; Alo[row][col0 + i + 1] = f2bf(v.y - bf2f(h1));
            Ahi[row][col0 + i + 2] = h2; Alo[row][col0 + i + 2] = f2bf(v.z - bf2f(h2));
            Ahi[row][col0 + i + 3] = h3; Alo[row][col0 + i + 3] = f2bf(v.w - bf2f(h3));
        }
    }
    __syncthreads();
    f32x4 acc[4][4];
    f32x4 zf = {0.f, 0.f, 0.f, 0.f};
    #pragma unroll
    for (int mi = 0; mi < 4; mi++)
        #pragma unroll
        for (int ni = 0; ni < 4; ni++) acc[mi][ni] = zf;
    #pragma unroll
    for (int q = 0; q < 4; q++) {
        int ko = q * 32 + lq * 8;
        bf16x8 ah[4], al[4];
        #pragma unroll
        for (int mi = 0; mi < 4; mi++) {
            ah[mi] = *(const bf16x8*)(const void*)&Ahi[mi * 16 + lr][ko];
            al[mi] = *(const bf16x8*)(const void*)&Alo[mi * 16 + lr][ko];
        }
        #pragma unroll
        for (int ni = 0; ni < 4; ni++) {
            size_t bo = (size_t)(w * 64 + ni * 16 + lr) * 128 + ko;
            bf16x8 bh = *(const bf16x8*)(const void*)(Bhi + bo);
            bf16x8 bl = *(const bf16x8*)(const void*)(Blo + bo);
            #pragma unroll
            for (int mi = 0; mi < 4; mi++) {
                acc[mi][ni] = __builtin_amdgcn_mfma_f32_16x16x32_bf16(al[mi], bh, acc[mi][ni], 0, 0, 0);
                acc[mi][ni] = __builtin_amdgcn_mfma_f32_16x16x32_bf16(ah[mi], bl, acc[mi][ni], 0, 0, 0);
                acc[mi][ni] = __builtin_amdgcn_mfma_f32_16x16x32_bf16(ah[mi], bh, acc[mi][ni], 0, 0, 0);
            }
        }
    }
    float asv[4], adv[4];
    #pragma unroll
    for (int ni = 0; ni < 4; ni++) {
        asv[ni] = a_src[w * 64 + ni * 16 + lr];
        adv[ni] = a_dst[w * 64 + ni * 16 + lr];
    }
    #pragma unroll
    for (int mi = 0; mi < 4; mi++) {
        f32x4 ps = zf, pd = zf;
        #pragma unroll
        for (int ni = 0; ni < 4; ni++)
            #pragma unroll
            for (int r = 0; r < 4; r++) {
                ps[r] += acc[mi][ni][r] * asv[ni];
                pd[r] += acc[mi][ni][r] * adv[ni];
            }
        #pragma unroll
        for (int m = 1; m < 16; m <<= 1)
            #pragma unroll
            for (int r = 0; r < 4; r++) {
                ps[r] += __shfl_xor(ps[r], m);
                pd[r] += __shfl_xor(pd[r], m);
            }
        #pragma unroll
        for (int r = 0; r < 4; r++) {
            int n = brow + mi * 16 + lq * 4 + r;
            if (lr == 0 && n < NN) { as1[n * 4 + w] = ps[r]; ad1[n * 4 + w] = pd[r]; }
        }
        #pragma unroll
        for (int ni = 0; ni < 4; ni++)
            #pragma unroll
            for (int r = 0; r < 4; r++) {
                int n = brow + mi * 16 + lq * 4 + r;
                if (n < NN)
                    h1b[(size_t)n * 256 + w * 64 + ni * 16 + lr] = f2bf(acc[mi][ni][r]);
            }
    }
}

// ---------------- layer-2 MFMA GEMM + fused alpha (single-bf16 A) ----------------
__global__ __launch_bounds__(256) void gemm2_mfma(
        const unsigned short* __restrict__ Ab,
        const unsigned short* __restrict__ Bhi, const unsigned short* __restrict__ Blo,
        const float* __restrict__ a_src, const float* __restrict__ a_dst,
        unsigned short* __restrict__ g2b, float* __restrict__ as2, float* __restrict__ ad2) {
    int tid = threadIdx.x;
    int w = tid >> 6, lane = tid & 63;
    int lq = lane >> 4, lr = lane & 15;
    int wrow = blockIdx.x * 128 + w * 32;
    f32x4 acc[2][4];
    f32x4 zf = {0.f, 0.f, 0.f, 0.f};
    #pragma unroll
    for (int mi = 0; mi < 2; mi++)
        #pragma unroll
        for (int ni = 0; ni < 4; ni++) acc[mi][ni] = zf;
    int ra = min(wrow + lr, NN - 1);
    int rb = min(wrow + 16 + lr, NN - 1);
    #pragma unroll
    for (int q = 0; q < 8; q++) {
        int ko = q * 32 + lq * 8;
        bf16x8 ah0 = *(const bf16x8*)(const void*)(Ab + (size_t)ra * 256 + ko);
        bf16x8 ah1 = *(const bf16x8*)(const void*)(Ab + (size_t)rb * 256 + ko);
        #pragma unroll
        for (int ni = 0; ni < 4; ni++) {
            size_t bo = (size_t)(ni * 16 + lr) * 256 + ko;
            bf16x8 bh = *(const bf16x8*)(const void*)(Bhi + bo);
            bf16x8 bl = *(const bf16x8*)(const void*)(Blo + bo);
            acc[0][ni] = __builtin_amdgcn_mfma_f32_16x16x32_bf16(ah0, bl, acc[0][ni], 0, 0, 0);
            acc[0][ni] = __builtin_amdgcn_mfma_f32_16x16x32_bf16(ah0, bh, acc[0][ni], 0, 0, 0);
            acc[1][ni] = __builtin_amdgcn_mfma_f32_16x16x32_bf16(ah1, bl, acc[1][ni], 0, 0, 0);
            acc[1][ni] = __builtin_amdgcn_mfma_f32_16x16x32_bf16(ah1, bh, acc[1][ni], 0, 0, 0);
        }
    }
    float asv[4], adv[4];
    #pragma unroll
    for (int ni = 0; ni < 4; ni++) {
        asv[ni] = a_src[ni * 16 + lr];
        adv[ni] = a_dst[ni * 16 + lr];
    }
    #pragma unroll
    for (int mi = 0; mi < 2; mi++) {
        f32x4 ps = zf, pd = zf;
        #pragma unroll
        for (int ni = 0; ni < 4; ni++)
            #pragma unroll
            for (int r = 0; r < 4; r++) {
                ps[r] += acc[mi][ni][r] * asv[ni];
                pd[r] += acc[mi][ni][r] * adv[ni];
            }
        #pragma unroll
        for (int m = 1; m < 16; m <<= 1)
            #pragma unroll
            for (int r = 0; r < 4; r++) {
                ps[r] += __shfl_xor(ps[r], m);
                pd[r] += __shfl_xor(pd[r], m);
            }
        #pragma unroll
        for (int r = 0; r < 4; r++) {
            int n = wrow + mi * 16 + lq * 4 + r;
            if (lr == 0 && n < NN) { as2[n] = ps[r]; ad2[n] = pd[r]; }
        }
        #pragma unroll
        for (int ni = 0; ni < 4; ni++)
            #pragma unroll
            for (int r = 0; r < 4; r++) {
                int n = wrow + mi * 16 + lq * 4 + r;
                if (n < NN)
                    g2b[(size_t)n * 64 + ni * 16 + lr] = f2bf(acc[mi][ni][r]);
            }
    }
}

// ---------------- layer-1 aggregation: edge-paired dot2 gather, unroll-8 ----------------
__global__ __launch_bounds__(256) void agg1_kernel(
        const unsigned short* __restrict__ h1b, const int* __restrict__ row_ptr,
        const unsigned short* __restrict__ csr_src, const float* __restrict__ as,
        const float* __restrict__ ad, const float* __restrict__ b1,
        unsigned short* __restrict__ h2b) {
    __shared__ int            ssrc[4][64];
    __shared__ unsigned short wbf[4][4][64];
    int tid = threadIdx.x;
    int wv = tid >> 6, lane = tid & 63;
    int n = blockIdx.x * 4 + wv;
    if (n >= NN) return;
    int start = row_ptr[n], end = row_ptr[n + 1];
    float4 adv = ((const float4*)ad)[n];
    int whead = lane >> 4;
    float4 acc = make_float4(0.f, 0.f, 0.f, 0.f);
    float d0 = 0.f, d1 = 0.f, d2 = 0.f, d3 = 0.f;
    for (int c0 = start; c0 < end; c0 += 64) {
        int m = min(64, end - c0);
        if (lane < m) {
            int s = (int)csr_src[c0 + lane];
            ssrc[wv][lane] = s;
            float4 asv = ((const float4*)as)[s];
            float e0 = asv.x + adv.x; e0 = e0 > 0.f ? e0 : 0.2f * e0; float x0 = __expf(e0);
            float e1 = asv.y + adv.y; e1 = e1 > 0.f ? e1 : 0.2f * e1; float x1 = __expf(e1);
            float e2 = asv.z + adv.z; e2 = e2 > 0.f ? e2 : 0.2f * e2; float x2 = __expf(e2);
            float e3 = asv.w + adv.w; e3 = e3 > 0.f ? e3 : 0.2f * e3; float x3 = __expf(e3);
            wbf[wv][0][lane] = f2bf(x0);
            wbf[wv][1][lane] = f2bf(x1);
            wbf[wv][2][lane] = f2bf(x2);
            wbf[wv][3][lane] = f2bf(x3);
            d0 += x0; d1 += x1; d2 += x2; d3 += x3;
        }
        int j = 0;
        for (; j + 8 <= m; j += 8) {
            int sj[8]; uint2 hj[8];
            #pragma unroll
            for (int u = 0; u < 8; u++) sj[u] = ssrc[wv][j + u];
            #pragma unroll
            for (int u = 0; u < 8; u++)
                hj[u] = ((const uint2*)h1b)[(size_t)sj[u] * 64 + lane];
            unsigned wp01 = *(const unsigned*)&wbf[wv][whead][j];
            unsigned wp23 = *(const unsigned*)&wbf[wv][whead][j + 2];
            unsigned wp45 = *(const unsigned*)&wbf[wv][whead][j + 4];
            unsigned wp67 = *(const unsigned*)&wbf[wv][whead][j + 6];
            acc.x = fdot2bf(prm(hj[1].x, hj[0].x, 0x05040100), wp01, acc.x);
            acc.y = fdot2bf(prm(hj[1].x, hj[0].x, 0x07060302), wp01, acc.y);
            acc.z = fdot2bf(prm(hj[1].y, hj[0].y, 0x05040100), wp01, acc.z);
            acc.w = fdot2bf(prm(hj[1].y, hj[0].y, 0x07060302), wp01, acc.w);
            acc.x = fdot2bf(prm(hj[3].x, hj[2].x, 0x05040100), wp23, acc.x);
            acc.y = fdot2bf(prm(hj[3].x, hj[2].x, 0x07060302), wp23, acc.y);
            acc.z = fdot2bf(prm(hj[3].y, hj[2].y, 0x05040100), wp23, acc.z);
            acc.w = fdot2bf(prm(hj[3].y, hj[2].y, 0x07060302), wp23, acc.w);
            acc.x = fdot2bf(prm(hj[5].x, hj[4].x, 0x05040100), wp45, acc.x);
            acc.y = fdot2bf(prm(hj[5].x, hj[4].x, 0x07060302), wp45, acc.y);
            acc.z = fdot2bf(prm(hj[5].y, hj[4].y, 0x05040100), wp45, acc.z);
            acc.w = fdot2bf(prm(hj[5].y, hj[4].y, 0x07060302), wp45, acc.w);
            acc.x = fdot2bf(prm(hj[7].x, hj[6].x, 0x05040100), wp67, acc.x);
            acc.y = fdot2bf(prm(hj[7].x, hj[6].x, 0x07060302), wp67, acc.y);
            acc.z = fdot2bf(prm(hj[7].y, hj[6].y, 0x05040100), wp67, acc.z);
            acc.w = fdot2bf(prm(hj[7].y, hj[6].y, 0x07060302), wp67, acc.w);
        }
        for (; j + 2 <= m; j += 2) {
            int s0 = ssrc[wv][j], s1 = ssrc[wv][j + 1];
            uint2 ha = ((const uint2*)h1b)[(size_t)s0 * 64 + lane];
            uint2 hb = ((const uint2*)h1b)[(size_t)s1 * 64 + lane];
            unsigned wp = *(const unsigned*)&wbf[wv][whead][j];
            acc.x = fdot2bf(prm(hb.x, ha.x, 0x05040100), wp, acc.x);
            acc.y = fdot2bf(prm(hb.x, ha.x, 0x07060302), wp, acc.y);
            acc.z = fdot2bf(prm(hb.y, ha.y, 0x05040100), wp, acc.z);
            acc.w = fdot2bf(prm(hb.y, ha.y, 0x07060302), wp, acc.w);
        }
        if (j < m) {
            int s = ssrc[wv][j];
            float w = bf2f(wbf[wv][whead][j]);
            ushort4 hv = ((const ushort4*)h1b)[(size_t)s * 64 + lane];
            acc.x += bf2f(hv.x) * w; acc.y += bf2f(hv.y) * w;
            acc.z += bf2f(hv.z) * w; acc.w += bf2f(hv.w) * w;
        }
    }
    #pragma unroll
    for (int off = 32; off; off >>= 1) {
        d0 += __shfl_down(d0, off); d1 += __shfl_down(d1, off);
        d2 += __shfl_down(d2, off); d3 += __shfl_down(d3, off);
    }
    d0 = __shfl(d0, 0); d1 = __shfl(d1, 0);
    d2 = __shfl(d2, 0); d3 = __shfl(d3, 0);
    float den = whead == 0 ? d0 : whead == 1 ? d1 : whead == 2 ? d2 : d3;
    float inv = 1.f / (den + 1e-16f);
    float4 bv = ((const float4*)b1)[lane];
    float4 r;
    r.x = acc.x * inv + bv.x; r.y = acc.y * inv + bv.y;
    r.z = acc.z * inv + bv.z; r.w = acc.w * inv + bv.w;
    r.x = r.x > 0.f ? r.x : expm1f(r.x);
    r.y = r.y > 0.f ? r.y : expm1f(r.y);
    r.z = r.z > 0.f ? r.z : expm1f(r.z);
    r.w = r.w > 0.f ? r.w : expm1f(r.w);
    ushort4 hv;
    hv.x = f2bf(r.x); hv.y = f2bf(r.y); hv.z = f2bf(r.z); hv.w = f2bf(r.w);
    ((ushort4*)h2b)[(size_t)n * 64 + lane] = hv;
}

// ---------------- layer-2 aggregation: edge-paired dot2 gather, unroll-8 ----------------
__global__ __launch_bounds__(256) void agg2_kernel(
        const unsigned short* __restrict__ g2b, const int* __restrict__ row_ptr,
        const unsigned short* __restrict__ csr_src, const float* __restrict__ as,
        const float* __restrict__ ad, const float* __restrict__ b2,
        float* __restrict__ out) {
    __shared__ int            ssrc[4][64];
    __shared__ unsigned short wbf[4][64];
    int tid = threadIdx.x;
    int wv = tid >> 6, lane = tid & 63;
    int n = blockIdx.x * 4 + wv;
    if (n >= NN) return;
    int start = row_ptr[n], end = row_ptr[n + 1];
    float adv = ad[n];
    float acc = 0.f;
    float den = 0.f;
    for (int c0 = start; c0 < end; c0 += 64) {
        int m = min(64, end - c0);
        if (lane < m) {
            int s = (int)csr_src[c0 + lane];
            ssrc[wv][lane] = s;
            float e = as[s] + adv;
            e = e > 0.f ? e : 0.2f * e;
            float x = __expf(e);
            wbf[wv][lane] = f2bf(x);
            den += x;
        }
        int j = 0;
        for (; j + 8 <= m; j += 8) {
            int sj[8]; unsigned gj[8];
            #pragma unroll
            for (int u = 0; u < 8; u++) sj[u] = ssrc[wv][j + u];
            #pragma unroll
            for (int u = 0; u < 8; u++)
                gj[u] = g2b[(size_t)sj[u] * 64 + lane];
            unsigned wp01 = *(const unsigned*)&wbf[wv][j];
            unsigned wp23 = *(const unsigned*)&wbf[wv][j + 2];
            unsigned wp45 = *(const unsigned*)&wbf[wv][j + 4];
            unsigned wp67 = *(const unsigned*)&wbf[wv][j + 6];
            acc = fdot2bf(prm(gj[1], gj[0], 0x05040100), wp01, acc);
            acc = fdot2bf(prm(gj[3], gj[2], 0x05040100), wp23, acc);
            acc = fdot2bf(prm(gj[5], gj[4], 0x05040100), wp45, acc);
            acc = fdot2bf(prm(gj[7], gj[6], 0x05040100), wp67, acc);
        }
        for (; j + 2 <= m; j += 2) {
            int s0 = ssrc[wv][j], s1 = ssrc[wv][j + 1];
            unsigned g0 = g2b[(size_t)s0 * 64 + lane];
            unsigned g1 = g2b[(size_t)s1 * 64 + lane];
            unsigned wp = *(const unsigned*)&wbf[wv][j];
            acc = fdot2bf(prm(g1, g0, 0x05040100), wp, acc);
        }
        if (j < m) {
            int s = ssrc[wv][j];
            acc += bf2f(g2b[(size_t)s * 64 + lane]) * bf2f(wbf[wv][j]);
        }
    }
    #pragma unroll
    for (int off = 32; off; off >>= 1) den += __shfl_down(den, off);
    den = __shfl(den, 0);
    float inv = 1.f / (den + 1e-16f);
    float r = acc * inv + b2[lane];
    out[(size_t)n * 64 + lane] = r > 0.f ? r : expm1f(r);
}

// ---------------- launch ----------------

extern "C" void kernel_launch(void* const* d_in, const int* in_sizes, int n_in,
                              void* d_out, int out_size, void* d_ws, size_t ws_size,
                              hipStream_t stream) {
    const float* x      = (const float*)d_in[0];
    const int*   ei     = (const int*)d_in[1];
    const float* W1     = (const float*)d_in[2];
    const float* a_src1 = (const float*)d_in[3];
    const float* a_dst1 = (const float*)d_in[4];
    const float* b1     = (const float*)d_in[5];
    const float* W2     = (const float*)d_in[6];
    const float* a_src2 = (const float*)d_in[7];
    const float* a_dst2 = (const float*)d_in[8];
    const float* b2     = (const float*)d_in[9];
    float* out = (float*)d_out;

    char* base = (char*)d_ws;
    size_t off = 0;
    auto alloc = [&](size_t bytes) -> void* {
        void* p = base + off;
        off = (off + bytes + 255) & ~(size_t)255;
        return p;
    };
    int*   deg     = (int*)alloc(NN * sizeof(int));
    unsigned long long* desc = (unsigned long long*)alloc(SCAN_BLOCKS * sizeof(unsigned long long));
    unsigned short* rank = (unsigned short*)alloc(EE * sizeof(unsigned short));
    int*   row_ptr = (int*)alloc((NN + 1) * sizeof(int));
    unsigned short* csr_src = (unsigned short*)alloc(EE * sizeof(unsigned short));
    unsigned short* W1Thi = (unsigned short*)alloc(256 * 128 * 2);
    unsigned short* W1Tlo = (unsigned short*)alloc(256 * 128 * 2);
    unsigned short* W2Thi = (unsigned short*)alloc(64 * 256 * 2);
    unsigned short* W2Tlo = (unsigned short*)alloc(64 * 256 * 2);
    unsigned short* h1b   = (unsigned short*)alloc((size_t)NN * 256 * 2);
    float* as1     = (float*)alloc((size_t)NN * 4 * sizeof(float));
    float* ad1     = (float*)alloc((size_t)NN * 4 * sizeof(float));
    unsigned short* h2b   = (unsigned short*)alloc((size_t)NN * 256 * 2);
    unsigned short* g2b   = (unsigned short*)alloc((size_t)NN * 64 * 2);
    float* as2     = (float*)alloc((size_t)NN * sizeof(float));
    float* ad2     = (float*)alloc((size_t)NN * sizeof(float));

    // deg and desc contiguous -> one memset clears both
    size_t clear_bytes = (size_t)((char*)(desc + SCAN_BLOCKS) - (char*)deg);
    hipMemsetAsync(deg, 0, clear_bytes, stream);

    front_kernel<<<EBLOCKS + 128 + 64, 256, 0, stream>>>(ei, deg, rank, W1, W1Thi, W1Tlo,
                                                         W2, W2Thi, W2Tlo);
    scan_fill_kernel<<<SCAN_BLOCKS, 256, 0, stream>>>(deg, desc, row_ptr);
    scatter_kernel<<<EBLOCKS, 256, 0, stream>>>(ei, rank, row_ptr, csr_src);

    gemm1_mfma<<<(NN + 63) / 64, 256, 0, stream>>>(x, W1Thi, W1Tlo,
                                                   a_src1, a_dst1, h1b, as1, ad1);
    agg1_kernel<<<(NN + 3) / 4, 256, 0, stream>>>(h1b, row_ptr, csr_src, as1, ad1, b1, h2b);
    gemm2_mfma<<<(NN + 127) / 128, 256, 0, stream>>>(h2b, W2Thi, W2Tlo,
                                                     a_src2, a_dst2, g2b, as2, ad2);
    agg2_kernel<<<(NN + 3) / 4, 256, 0, stream>>>(g2b, row_ptr, csr_src, as2, ad2, b2, out);
}